// Round 1
// baseline (3743.760 us; speedup 1.0000x reference)
//
#include <hip/hip_runtime.h>
#include <math.h>

#define SEQ 1024
#define DIM 1024
#define NH 16
#define HD 64
#define NB 2

// ---------------------------------------------------------------------------
// pos[l, i]: TENER positional table, length 2S, dim 64.
// position p = l - S; half = 32; div_term[i] = exp(-i*ln(10000)/31)
// pos[l, 0:32] = sin(p*dt), pos[l, 32:64] = cos(p*dt)
// ---------------------------------------------------------------------------
__global__ void pos_kernel(float* __restrict__ pos) {
    int l = blockIdx.x;      // 0 .. 2*SEQ-1
    int i = threadIdx.x;     // 0 .. 63
    float p = (float)(l - SEQ);
    int hi = (i < 32) ? i : (i - 32);
    float dt = expf((float)hi * (-logf(10000.0f) / 31.0f));
    float ang = p * dt;
    pos[(size_t)l * HD + i] = (i < 32) ? sinf(ang) : cosf(ang);
}

// vbr[h, l] = sum_d v_bias[h,d] * pos[l,d]
__global__ void vbr_kernel(const float* __restrict__ v_bias,
                           const float* __restrict__ pos,
                           float* __restrict__ vbr) {
    int idx = blockIdx.x * blockDim.x + threadIdx.x;
    if (idx >= NH * 2 * SEQ) return;
    int h = idx / (2 * SEQ);
    int l = idx % (2 * SEQ);
    float acc = 0.f;
    #pragma unroll 16
    for (int d = 0; d < HD; ++d)
        acc += v_bias[h * HD + d] * pos[(size_t)l * HD + d];
    vbr[idx] = acc;
}

// ---------------------------------------------------------------------------
// C[m,n] = sum_k A[m,k] * W[n,k] + bias[n]   (A:[M,K], W:[N,K])
// 64x64 tile, 256 threads, each thread 4x4, K-tile 16.
// ---------------------------------------------------------------------------
__global__ __launch_bounds__(256) void gemm_bt(
    const float* __restrict__ A, const float* __restrict__ W,
    const float* __restrict__ bias, float* __restrict__ C,
    int M, int N, int K)
{
    __shared__ float As[16][64];
    __shared__ float Ws[16][64];

    int tid = threadIdx.x;
    int tx = tid & 15, ty = tid >> 4;
    int m0 = blockIdx.y * 64, n0 = blockIdx.x * 64;

    int lm = tid >> 2;            // 0..63
    int lk = (tid & 3) * 4;       // 0,4,8,12

    float acc[4][4] = {};

    for (int kk = 0; kk < K; kk += 16) {
        float4 av = *(const float4*)&A[(size_t)(m0 + lm) * K + kk + lk];
        float4 wv = *(const float4*)&W[(size_t)(n0 + lm) * K + kk + lk];
        As[lk + 0][lm] = av.x; As[lk + 1][lm] = av.y;
        As[lk + 2][lm] = av.z; As[lk + 3][lm] = av.w;
        Ws[lk + 0][lm] = wv.x; Ws[lk + 1][lm] = wv.y;
        Ws[lk + 2][lm] = wv.z; Ws[lk + 3][lm] = wv.w;
        __syncthreads();
        #pragma unroll
        for (int k = 0; k < 16; ++k) {
            float4 a = *(const float4*)&As[k][ty * 4];
            float4 b = *(const float4*)&Ws[k][tx * 4];
            float ar[4] = {a.x, a.y, a.z, a.w};
            float br[4] = {b.x, b.y, b.z, b.w};
            #pragma unroll
            for (int i = 0; i < 4; ++i)
                #pragma unroll
                for (int j = 0; j < 4; ++j)
                    acc[i][j] += ar[i] * br[j];
        }
        __syncthreads();
    }

    #pragma unroll
    for (int i = 0; i < 4; ++i) {
        int m = m0 + ty * 4 + i;
        float4 bv4 = *(const float4*)&bias[n0 + tx * 4];
        float4 o;
        o.x = acc[i][0] + bv4.x;
        o.y = acc[i][1] + bv4.y;
        o.z = acc[i][2] + bv4.z;
        o.w = acc[i][3] + bv4.w;
        *(float4*)&C[(size_t)m * N + n0 + tx * 4] = o;
    }
}

// ---------------------------------------------------------------------------
// Attention: one block per (b,h,q) row.
// score[j] = sum_d q[d]*(k[j,d] + pos[S+j-q, d]) + vbr[h, S+j-q]
// softmax over j, then out[dd] = sum_j p[j]*v[j,dd]
// ---------------------------------------------------------------------------
__global__ __launch_bounds__(256) void attn_kernel(
    const float* __restrict__ qp,    // [B,S,D] projected q
    const float* __restrict__ key,   // [B,S,D] raw key
    const float* __restrict__ vp,    // [B,S,D] projected v
    const float* __restrict__ pos,   // [2S, 64]
    const float* __restrict__ vbr,   // [H, 2S]
    float* __restrict__ x)           // [B,S,D]
{
    int bid = blockIdx.x;
    int qi = bid & (SEQ - 1);
    int h  = (bid >> 10) & (NH - 1);
    int b  = bid >> 14;

    __shared__ float qs[HD];
    __shared__ float sc[SEQ];
    __shared__ float red[256];

    int tid = threadIdx.x;
    if (tid < HD)
        qs[tid] = qp[((size_t)(b * SEQ + qi)) * DIM + h * HD + tid];
    __syncthreads();

    float4 qv[16];
    const float4* q4 = (const float4*)qs;
    #pragma unroll
    for (int t = 0; t < 16; ++t) qv[t] = q4[t];

    // --- scores ---
    for (int j = tid; j < SEQ; j += 256) {
        int l = SEQ + j - qi;   // in [1, 2S-1]
        const float4* kp = (const float4*)(key + ((size_t)(b * SEQ + j)) * DIM + h * HD);
        const float4* pp = (const float4*)(pos + (size_t)l * HD);
        float acc = 0.f;
        #pragma unroll
        for (int t = 0; t < 16; ++t) {
            float4 kk = kp[t];
            float4 pv = pp[t];
            acc += qv[t].x * (kk.x + pv.x);
            acc += qv[t].y * (kk.y + pv.y);
            acc += qv[t].z * (kk.z + pv.z);
            acc += qv[t].w * (kk.w + pv.w);
        }
        sc[j] = acc + vbr[h * 2 * SEQ + l];
    }
    __syncthreads();

    // --- max ---
    float m = -INFINITY;
    for (int j = tid; j < SEQ; j += 256) m = fmaxf(m, sc[j]);
    red[tid] = m;
    __syncthreads();
    for (int s = 128; s > 0; s >>= 1) {
        if (tid < s) red[tid] = fmaxf(red[tid], red[tid + s]);
        __syncthreads();
    }
    m = red[0];
    __syncthreads();

    // --- exp + sum ---
    float sum = 0.f;
    for (int j = tid; j < SEQ; j += 256) {
        float e = expf(sc[j] - m);
        sc[j] = e;
        sum += e;
    }
    red[tid] = sum;
    __syncthreads();
    for (int s = 128; s > 0; s >>= 1) {
        if (tid < s) red[tid] += red[tid + s];
        __syncthreads();
    }
    float inv = 1.f / red[0];
    __syncthreads();

    // --- PV: thread (g,dd), g = tid>>6 strides j, dd = tid&63 ---
    int dd = tid & 63;
    int g  = tid >> 6;
    float acc = 0.f;
    for (int j = g; j < SEQ; j += 4)
        acc += sc[j] * vp[((size_t)(b * SEQ + j)) * DIM + h * HD + dd];
    red[g * 64 + dd] = acc;
    __syncthreads();
    if (tid < 64) {
        float r = (red[tid] + red[64 + tid] + red[128 + tid] + red[192 + tid]) * inv;
        x[((size_t)(b * SEQ + qi)) * DIM + h * HD + tid] = r;
    }
}

// ---------------------------------------------------------------------------
extern "C" void kernel_launch(void* const* d_in, const int* in_sizes, int n_in,
                              void* d_out, int out_size, void* d_ws, size_t ws_size,
                              hipStream_t stream) {
    const float* query  = (const float*)d_in[0];
    const float* key    = (const float*)d_in[1];
    const float* value  = (const float*)d_in[2];
    // d_in[3]: mask — unused (reference softmax is unmasked)
    const float* Wq     = (const float*)d_in[4];
    const float* bq     = (const float*)d_in[5];
    const float* Wv     = (const float*)d_in[6];
    const float* bv     = (const float*)d_in[7];
    const float* Wo     = (const float*)d_in[8];
    const float* bo     = (const float*)d_in[9];
    const float* v_bias = (const float*)d_in[10];

    float* out = (float*)d_out;
    float* ws  = (float*)d_ws;

    // workspace layout (floats): pos | vbr | qp | vp | x  (~25.8 MB total)
    float* pos = ws;
    float* vbr = pos + (size_t)2 * SEQ * HD;          // 2048*64
    float* qp  = vbr + (size_t)NH * 2 * SEQ;          // 16*2048
    float* vp  = qp  + (size_t)NB * SEQ * DIM;        // 2M
    float* x   = vp  + (size_t)NB * SEQ * DIM;        // 2M

    pos_kernel<<<2 * SEQ, HD, 0, stream>>>(pos);
    vbr_kernel<<<(NH * 2 * SEQ + 255) / 256, 256, 0, stream>>>(v_bias, pos, vbr);

    dim3 ggrid(DIM / 64, NB * SEQ / 64);
    gemm_bt<<<ggrid, 256, 0, stream>>>(query, Wq, bq, qp, NB * SEQ, DIM, DIM);
    gemm_bt<<<ggrid, 256, 0, stream>>>(value, Wv, bv, vp, NB * SEQ, DIM, DIM);

    attn_kernel<<<NB * NH * SEQ, 256, 0, stream>>>(qp, key, vp, pos, vbr, x);

    gemm_bt<<<ggrid, 256, 0, stream>>>(x, Wo, bo, out, NB * SEQ, DIM, DIM);
}

// Round 3
// 401.222 us; speedup vs baseline: 9.3309x; 9.3309x over previous
//
#include <hip/hip_runtime.h>
#include <math.h>

#define SEQ 1024
#define DIM 1024
#define NH 16
#define HD 64
#define NB 2

typedef __attribute__((ext_vector_type(8))) short bf16x8;
typedef __attribute__((ext_vector_type(4))) float f32x4;
typedef __attribute__((ext_vector_type(8))) unsigned short ushort8;
typedef __attribute__((ext_vector_type(4))) unsigned short ushort4v;

#define DT_CONST (-0.2971077539347156f)   // -ln(10000)/31

__device__ __forceinline__ unsigned short f2bf(float x) {
    unsigned u = __float_as_uint(x);
    return (unsigned short)((u + 0x7fffu + ((u >> 16) & 1u)) >> 16);
}
__device__ __forceinline__ float bf2f(unsigned short h) {
    return __uint_as_float(((unsigned)h) << 16);
}
__device__ __forceinline__ void bfsplit(float x, unsigned short& hi, unsigned short& lo) {
    hi = f2bf(x);
    lo = f2bf(x - bf2f(hi));
}

// ---------------------------------------------------------------------------
// f32 GEMM: C[m,n] = sum_k A[m,k]*W[n,k] + bias[n]
// ---------------------------------------------------------------------------
__global__ __launch_bounds__(256) void gemm_bt(
    const float* __restrict__ A, const float* __restrict__ W,
    const float* __restrict__ bias, float* __restrict__ C,
    int M, int N, int K)
{
    __shared__ float As[16][64];
    __shared__ float Ws[16][64];

    int tid = threadIdx.x;
    int tx = tid & 15, ty = tid >> 4;
    int m0 = blockIdx.y * 64, n0 = blockIdx.x * 64;
    int lm = tid >> 2;
    int lk = (tid & 3) * 4;

    float acc[4][4] = {};

    for (int kk = 0; kk < K; kk += 16) {
        float4 av = *(const float4*)&A[(size_t)(m0 + lm) * K + kk + lk];
        float4 wv = *(const float4*)&W[(size_t)(n0 + lm) * K + kk + lk];
        As[lk + 0][lm] = av.x; As[lk + 1][lm] = av.y;
        As[lk + 2][lm] = av.z; As[lk + 3][lm] = av.w;
        Ws[lk + 0][lm] = wv.x; Ws[lk + 1][lm] = wv.y;
        Ws[lk + 2][lm] = wv.z; Ws[lk + 3][lm] = wv.w;
        __syncthreads();
        #pragma unroll
        for (int k = 0; k < 16; ++k) {
            float4 a = *(const float4*)&As[k][ty * 4];
            float4 b = *(const float4*)&Ws[k][tx * 4];
            float ar[4] = {a.x, a.y, a.z, a.w};
            float br[4] = {b.x, b.y, b.z, b.w};
            #pragma unroll
            for (int i = 0; i < 4; ++i)
                #pragma unroll
                for (int j = 0; j < 4; ++j)
                    acc[i][j] += ar[i] * br[j];
        }
        __syncthreads();
    }

    #pragma unroll
    for (int i = 0; i < 4; ++i) {
        int m = m0 + ty * 4 + i;
        float4 bv4 = *(const float4*)&bias[n0 + tx * 4];
        float4 o;
        o.x = acc[i][0] + bv4.x;
        o.y = acc[i][1] + bv4.y;
        o.z = acc[i][2] + bv4.z;
        o.w = acc[i][3] + bv4.w;
        *(float4*)&C[(size_t)m * N + n0 + tx * 4] = o;
    }
}

// ---------------------------------------------------------------------------
// K'' trig table: Kt[j, c] = c<32 ? sin(j*dt_c) : cos(j*dt_{c-32}), split hi/lo
// ---------------------------------------------------------------------------
__global__ void prep_ktrig(unsigned short* __restrict__ Kth,
                           unsigned short* __restrict__ Ktl) {
    int idx = blockIdx.x * 256 + threadIdx.x;   // [0, SEQ*64)
    int j = idx >> 6;
    int c = idx & 63;
    int i = c & 31;
    float dt = __expf((float)i * DT_CONST);
    float ang = (float)j * dt;
    float val = (c < 32) ? sinf(ang) : cosf(ang);
    unsigned short hi, lo;
    bfsplit(val, hi, lo);
    Kth[idx] = hi;
    Ktl[idx] = lo;
}

// ---------------------------------------------------------------------------
// Q'' prep: Qh/Ql [B,H,S,128] bf16 hi/lo.
// d<64: projected q head.  d in [64,96): sin-coef.  d in [96,128): cos-coef.
// ---------------------------------------------------------------------------
__global__ __launch_bounds__(256) void prep_q(
    const float* __restrict__ qp,      // [B,S,D]
    const float* __restrict__ v_bias,  // [H,64]
    unsigned short* __restrict__ Qh,
    unsigned short* __restrict__ Ql)
{
    int tid = threadIdx.x;
    int sub = tid >> 7;            // 0..1
    int d = tid & 127;
    int row = blockIdx.x * 2 + sub;    // [0, B*H*S)
    int b = row >> 14;
    int h = (row >> 10) & 15;
    int q = row & 1023;

    float val;
    if (d < 64) {
        val = qp[((size_t)(b * SEQ + q)) * DIM + h * HD + d];
    } else {
        int i = d & 31;
        float qs = qp[((size_t)(b * SEQ + q)) * DIM + h * HD + i];
        float qc = qp[((size_t)(b * SEQ + q)) * DIM + h * HD + 32 + i];
        float vs = v_bias[h * HD + i];
        float vc = v_bias[h * HD + 32 + i];
        float u = qs + vs;
        float w = qc + vc;
        float dt = __expf((float)i * DT_CONST);
        float ang = (float)q * dt;
        float Cq = cosf(ang), Sq = sinf(ang);
        val = (d < 96) ? (u * Cq + w * Sq) : (w * Cq - u * Sq);
    }
    unsigned short hi, lo;
    bfsplit(val, hi, lo);
    size_t o = ((size_t)row) * 128 + d;
    Qh[o] = hi;
    Ql[o] = lo;
}

// ---------------------------------------------------------------------------
// Flash attention with MFMA. Block = 256 thr (4 waves), 64 q-rows, one (b,h).
// QK^T in split-bf16 (3 MFMA per chunk), PV in plain bf16.
// ---------------------------------------------------------------------------
#define LDK 136   // K'' / Q'' LDS row stride (shorts); 272B = 17*16B
#define LDV 72    // Vt / Ps row stride (shorts); 144B = 9*16B

__global__ __launch_bounds__(256) void attn_mfma(
    const float* __restrict__ key,   // [B,S,D]
    const float* __restrict__ vp,    // [B,S,D]
    const unsigned short* __restrict__ Qh,   // [B,H,S,128]
    const unsigned short* __restrict__ Ql,
    const unsigned short* __restrict__ Kth,  // [S,64]
    const unsigned short* __restrict__ Ktl,
    float* __restrict__ xa)          // [B,S,D]
{
    __shared__ unsigned short Ksh[64][LDK];
    __shared__ unsigned short Ksl[64][LDK];
    __shared__ unsigned short Vt[64][LDV];
    __shared__ unsigned short Ps[64][LDV];

    int tid = threadIdx.x;
    int w = tid >> 6;
    int lane = tid & 63;
    int l16 = lane & 15;
    int quad = lane >> 4;

    int bid = blockIdx.x;
    int qt = bid & 15;
    int h = (bid >> 4) & 15;
    int b = bid >> 8;
    int q0 = qt << 6;

    // ---- stage Q'' into Ksh/Ksl, pull A-fragments to registers ----
    {
        const unsigned short* gq = Qh + (((size_t)(b * NH + h)) * SEQ + q0) * 128;
        const unsigned short* gl = Ql + (((size_t)(b * NH + h)) * SEQ + q0) * 128;
        #pragma unroll
        for (int c = tid; c < 1024; c += 256) {
            int r = c >> 4, s8 = (c & 15) << 3;
            *(ushort8*)&Ksh[r][s8] = *(const ushort8*)&gq[r * 128 + s8];
            *(ushort8*)&Ksl[r][s8] = *(const ushort8*)&gl[r * 128 + s8];
        }
    }
    __syncthreads();

    bf16x8 ah[4], al[4];
    #pragma unroll
    for (int c = 0; c < 4; ++c) {
        ah[c] = *(const bf16x8*)&Ksh[w * 16 + l16][c * 32 + quad * 8];
        al[c] = *(const bf16x8*)&Ksl[w * 16 + l16][c * 32 + quad * 8];
    }
    __syncthreads();

    f32x4 oacc[4];
    #pragma unroll
    for (int nb = 0; nb < 4; ++nb) oacc[nb] = (f32x4){0.f, 0.f, 0.f, 0.f};
    float mval[4] = {-INFINITY, -INFINITY, -INFINITY, -INFINITY};
    float lval[4] = {0.f, 0.f, 0.f, 0.f};

    for (int jt = 0; jt < 16; ++jt) {
        int j0 = jt << 6;

        // ---- stage K'' tile (key f32 -> hi/lo split; trig copy) + V tile ----
        #pragma unroll
        for (int cc = tid; cc < 1024; cc += 256) {    // key part: 64x64 f32
            int r = cc >> 4, c4 = (cc & 15) << 2;
            float4 kv = *(const float4*)&key[((size_t)(b * SEQ + j0 + r)) * DIM + h * HD + c4];
            unsigned short hx, lx, hy, ly, hz, lz, hw, lw;
            bfsplit(kv.x, hx, lx);
            bfsplit(kv.y, hy, ly);
            bfsplit(kv.z, hz, lz);
            bfsplit(kv.w, hw, lw);
            ushort4v hi4, lo4;
            hi4.x = hx; hi4.y = hy; hi4.z = hz; hi4.w = hw;
            lo4.x = lx; lo4.y = ly; lo4.z = lz; lo4.w = lw;
            *(ushort4v*)&Ksh[r][c4] = hi4;
            *(ushort4v*)&Ksl[r][c4] = lo4;
        }
        #pragma unroll
        for (int cc = tid; cc < 512; cc += 256) {     // trig part: 64x64 shorts
            int r = cc >> 3, s8 = (cc & 7) << 3;
            *(ushort8*)&Ksh[r][64 + s8] = *(const ushort8*)&Kth[(size_t)(j0 + r) * 64 + s8];
            *(ushort8*)&Ksl[r][64 + s8] = *(const ushort8*)&Ktl[(size_t)(j0 + r) * 64 + s8];
        }
        #pragma unroll
        for (int ii = 0; ii < 16; ++ii) {             // V part, transposed
            int idx = tid + ii * 256;
            int r = idx >> 6, dd = idx & 63;
            float v = vp[((size_t)(b * SEQ + j0 + r)) * DIM + h * HD + dd];
            Vt[dd][r] = f2bf(v);
        }
        __syncthreads();

        // ---- QK^T: S[16 x 64] per wave, split-bf16 ----
        f32x4 sacc[4];
        #pragma unroll
        for (int nb = 0; nb < 4; ++nb) {
            sacc[nb] = (f32x4){0.f, 0.f, 0.f, 0.f};
            #pragma unroll
            for (int c = 0; c < 4; ++c) {
                bf16x8 bh = *(const bf16x8*)&Ksh[nb * 16 + l16][c * 32 + quad * 8];
                bf16x8 bl = *(const bf16x8*)&Ksl[nb * 16 + l16][c * 32 + quad * 8];
                sacc[nb] = __builtin_amdgcn_mfma_f32_16x16x32_bf16(ah[c], bh, sacc[nb], 0, 0, 0);
                sacc[nb] = __builtin_amdgcn_mfma_f32_16x16x32_bf16(al[c], bh, sacc[nb], 0, 0, 0);
                sacc[nb] = __builtin_amdgcn_mfma_f32_16x16x32_bf16(ah[c], bl, sacc[nb], 0, 0, 0);
            }
        }

        // ---- online softmax (rows = quad*4 + reg, cols across 16 lanes) ----
        #pragma unroll
        for (int r = 0; r < 4; ++r) {
            float v = fmaxf(fmaxf(sacc[0][r], sacc[1][r]), fmaxf(sacc[2][r], sacc[3][r]));
            #pragma unroll
            for (int mask = 1; mask < 16; mask <<= 1)
                v = fmaxf(v, __shfl_xor(v, mask, 64));
            float mnew = fmaxf(mval[r], v);
            float alpha = __expf(mval[r] - mnew);
            float p0 = __expf(sacc[0][r] - mnew);
            float p1 = __expf(sacc[1][r] - mnew);
            float p2 = __expf(sacc[2][r] - mnew);
            float p3 = __expf(sacc[3][r] - mnew);
            float rs = (p0 + p1) + (p2 + p3);
            #pragma unroll
            for (int mask = 1; mask < 16; mask <<= 1)
                rs += __shfl_xor(rs, mask, 64);
            lval[r] = lval[r] * alpha + rs;
            mval[r] = mnew;
            int prow = w * 16 + quad * 4 + r;
            Ps[prow][0 * 16 + l16] = f2bf(p0);
            Ps[prow][1 * 16 + l16] = f2bf(p1);
            Ps[prow][2 * 16 + l16] = f2bf(p2);
            Ps[prow][3 * 16 + l16] = f2bf(p3);
            oacc[0][r] *= alpha;
            oacc[1][r] *= alpha;
            oacc[2][r] *= alpha;
            oacc[3][r] *= alpha;
        }
        // no barrier needed: each wave reads back only its own 16 Ps rows,
        // and Vt is stable since the staging barrier.

        // ---- PV: O[16 x 64] += P[16 x 64] * V[64 x 64] ----
        #pragma unroll
        for (int nb = 0; nb < 4; ++nb) {
            #pragma unroll
            for (int kc = 0; kc < 2; ++kc) {
                bf16x8 a = *(const bf16x8*)&Ps[w * 16 + l16][kc * 32 + quad * 8];
                bf16x8 bv = *(const bf16x8*)&Vt[nb * 16 + l16][kc * 32 + quad * 8];
                oacc[nb] = __builtin_amdgcn_mfma_f32_16x16x32_bf16(a, bv, oacc[nb], 0, 0, 0);
            }
        }
        __syncthreads();   // protect Ksh/Ksl/Vt/Ps before next staging
    }

    // ---- epilogue: divide by l, write x [B,S,H*dv] ----
    #pragma unroll
    for (int r = 0; r < 4; ++r) {
        float inv = 1.f / lval[r];
        int qrow = q0 + w * 16 + quad * 4 + r;
        #pragma unroll
        for (int nb = 0; nb < 4; ++nb) {
            xa[((size_t)(b * SEQ + qrow)) * DIM + h * HD + nb * 16 + l16] = oacc[nb][r] * inv;
        }
    }
}

// ---------------------------------------------------------------------------
extern "C" void kernel_launch(void* const* d_in, const int* in_sizes, int n_in,
                              void* d_out, int out_size, void* d_ws, size_t ws_size,
                              hipStream_t stream) {
    const float* query  = (const float*)d_in[0];
    const float* key    = (const float*)d_in[1];
    const float* value  = (const float*)d_in[2];
    // d_in[3]: mask — unused (reference softmax is unmasked)
    const float* Wq     = (const float*)d_in[4];
    const float* bq     = (const float*)d_in[5];
    const float* Wv     = (const float*)d_in[6];
    const float* bv     = (const float*)d_in[7];
    const float* Wo     = (const float*)d_in[8];
    const float* bo     = (const float*)d_in[9];
    const float* v_bias = (const float*)d_in[10];

    float* out = (float*)d_out;

    // workspace layout
    float* qp = (float*)d_ws;                              // [B,S,D] f32 (reused as xa)
    float* vp = qp + (size_t)NB * SEQ * DIM;               // [B,S,D] f32
    unsigned short* Qh  = (unsigned short*)(vp + (size_t)NB * SEQ * DIM);
    unsigned short* Ql  = Qh + (size_t)NB * NH * SEQ * 128;
    unsigned short* Kth = Ql + (size_t)NB * NH * SEQ * 128;
    unsigned short* Ktl = Kth + (size_t)SEQ * 64;

    dim3 ggrid(DIM / 64, NB * SEQ / 64);
    gemm_bt<<<ggrid, 256, 0, stream>>>(query, Wq, bq, qp, NB * SEQ, DIM, DIM);
    gemm_bt<<<ggrid, 256, 0, stream>>>(value, Wv, bv, vp, NB * SEQ, DIM, DIM);

    prep_ktrig<<<SEQ * 64 / 256, 256, 0, stream>>>(Kth, Ktl);
    prep_q<<<NB * NH * SEQ / 2, 256, 0, stream>>>(qp, v_bias, Qh, Ql);

    float* xa = qp;   // qp no longer needed after prep_q
    attn_mfma<<<NB * NH * (SEQ / 64), 256, 0, stream>>>(key, vp, Qh, Ql, Kth, Ktl, xa);

    gemm_bt<<<ggrid, 256, 0, stream>>>(xa, Wo, bo, out, NB * SEQ, DIM, DIM);
}

// Round 4
// 247.068 us; speedup vs baseline: 15.1527x; 1.6239x over previous
//
#include <hip/hip_runtime.h>
#include <math.h>

#define SEQ 1024
#define DIM 1024
#define NH 16
#define HD 64
#define NB 2

typedef __attribute__((ext_vector_type(8))) short bf16x8;
typedef __attribute__((ext_vector_type(4))) float f32x4;
typedef __attribute__((ext_vector_type(8))) unsigned short ushort8;
typedef __attribute__((ext_vector_type(4))) unsigned short ushort4v;

#define DT_CONST (-0.2971077539347156f)   // -ln(10000)/31

__device__ __forceinline__ unsigned short f2bf(float x) {
    unsigned u = __float_as_uint(x);
    return (unsigned short)((u + 0x7fffu + ((u >> 16) & 1u)) >> 16);
}
__device__ __forceinline__ float bf2f(unsigned short h) {
    return __uint_as_float(((unsigned)h) << 16);
}
__device__ __forceinline__ void bfsplit(float x, unsigned short& hi, unsigned short& lo) {
    hi = f2bf(x);
    lo = f2bf(x - bf2f(hi));
}

// ---------------------------------------------------------------------------
// Conversion passes: f32 -> bf16 (hi) or split bf16 (hi+lo). 4 elems/thread.
// ---------------------------------------------------------------------------
__global__ __launch_bounds__(256) void conv_split(
    const float* __restrict__ x, unsigned short* __restrict__ h,
    unsigned short* __restrict__ l, int n)
{
    int i = (blockIdx.x * 256 + threadIdx.x) * 4;
    if (i >= n) return;
    float4 v = *(const float4*)&x[i];
    unsigned short hx, lx, hy, ly, hz, lz, hw, lw;
    bfsplit(v.x, hx, lx); bfsplit(v.y, hy, ly);
    bfsplit(v.z, hz, lz); bfsplit(v.w, hw, lw);
    ushort4v hv, lv;
    hv.x = hx; hv.y = hy; hv.z = hz; hv.w = hw;
    lv.x = lx; lv.y = ly; lv.z = lz; lv.w = lw;
    *(ushort4v*)&h[i] = hv;
    *(ushort4v*)&l[i] = lv;
}

__global__ __launch_bounds__(256) void conv_plain(
    const float* __restrict__ x, unsigned short* __restrict__ h, int n)
{
    int i = (blockIdx.x * 256 + threadIdx.x) * 4;
    if (i >= n) return;
    float4 v = *(const float4*)&x[i];
    ushort4v hv;
    hv.x = f2bf(v.x); hv.y = f2bf(v.y); hv.z = f2bf(v.z); hv.w = f2bf(v.w);
    *(ushort4v*)&h[i] = hv;
}

// ---------------------------------------------------------------------------
// MFMA GEMM: C[m,n] = sum_k A[m,k]*W[n,k] + bias[n].  A:[M,K], W:[N,K] bf16.
// Tile 128x64, BK=32, 4 waves (2x2), each wave 64x32 (4x2 16x16 tiles).
// SPLIT: A/W given as hi+lo pairs; 3 MFMA per tile (AhBh + AlBh + AhBl).
// ---------------------------------------------------------------------------
template<bool SPLIT, bool OUT_BF16>
__global__ __launch_bounds__(256) void gemm_mfma(
    const unsigned short* __restrict__ Ah, const unsigned short* __restrict__ Al,
    const unsigned short* __restrict__ Wh, const unsigned short* __restrict__ Wl,
    const float* __restrict__ bias, float* __restrict__ Cf,
    unsigned short* __restrict__ Cb, int M, int N, int K)
{
    __shared__ unsigned short sAh[128][32];
    __shared__ unsigned short sAl[SPLIT ? 128 : 1][32];
    __shared__ unsigned short sWh[64][32];
    __shared__ unsigned short sWl[SPLIT ? 64 : 1][32];

    int tid = threadIdx.x;
    int lane = tid & 63;
    int w = tid >> 6;
    int l16 = lane & 15, quad = lane >> 4;
    int wm = w & 1, wn = w >> 1;
    int m0 = blockIdx.y * 128, n0 = blockIdx.x * 64;

    int ar = tid >> 2, ap = (tid & 3) << 3;   // A slots: rows ar, ar+64

    const unsigned short* pAh0 = Ah + (size_t)(m0 + ar) * K + ap;
    const unsigned short* pAh1 = pAh0 + (size_t)64 * K;
    const unsigned short* pWh  = Wh + (size_t)(n0 + ar) * K + ap;
    const unsigned short* pAl0 = nullptr, *pAl1 = nullptr, *pWl = nullptr;
    if (SPLIT) {
        pAl0 = Al + (size_t)(m0 + ar) * K + ap;
        pAl1 = pAl0 + (size_t)64 * K;
        pWl  = Wl + (size_t)(n0 + ar) * K + ap;
    }

    f32x4 acc[4][2];
    #pragma unroll
    for (int mt = 0; mt < 4; ++mt)
        #pragma unroll
        for (int nt = 0; nt < 2; ++nt)
            acc[mt][nt] = (f32x4){0.f, 0.f, 0.f, 0.f};

    for (int kk = 0; kk < K; kk += 32) {
        ushort8 a0 = *(const ushort8*)(pAh0 + kk);
        ushort8 a1 = *(const ushort8*)(pAh1 + kk);
        ushort8 b0 = *(const ushort8*)(pWh + kk);
        ushort8 a0l, a1l, b0l;
        if (SPLIT) {
            a0l = *(const ushort8*)(pAl0 + kk);
            a1l = *(const ushort8*)(pAl1 + kk);
            b0l = *(const ushort8*)(pWl + kk);
        }
        __syncthreads();
        *(ushort8*)&sAh[ar][ap] = a0;
        *(ushort8*)&sAh[ar + 64][ap] = a1;
        *(ushort8*)&sWh[ar][ap] = b0;
        if (SPLIT) {
            *(ushort8*)&sAl[ar][ap] = a0l;
            *(ushort8*)&sAl[ar + 64][ap] = a1l;
            *(ushort8*)&sWl[ar][ap] = b0l;
        }
        __syncthreads();

        bf16x8 af[4], bf[2], afl[4], bfl[2];
        #pragma unroll
        for (int mt = 0; mt < 4; ++mt) {
            af[mt] = *(const bf16x8*)&sAh[wm * 64 + mt * 16 + l16][quad * 8];
            if (SPLIT) afl[mt] = *(const bf16x8*)&sAl[wm * 64 + mt * 16 + l16][quad * 8];
        }
        #pragma unroll
        for (int nt = 0; nt < 2; ++nt) {
            bf[nt] = *(const bf16x8*)&sWh[wn * 32 + nt * 16 + l16][quad * 8];
            if (SPLIT) bfl[nt] = *(const bf16x8*)&sWl[wn * 32 + nt * 16 + l16][quad * 8];
        }
        #pragma unroll
        for (int mt = 0; mt < 4; ++mt)
            #pragma unroll
            for (int nt = 0; nt < 2; ++nt) {
                acc[mt][nt] = __builtin_amdgcn_mfma_f32_16x16x32_bf16(af[mt], bf[nt], acc[mt][nt], 0, 0, 0);
                if (SPLIT) {
                    acc[mt][nt] = __builtin_amdgcn_mfma_f32_16x16x32_bf16(afl[mt], bf[nt], acc[mt][nt], 0, 0, 0);
                    acc[mt][nt] = __builtin_amdgcn_mfma_f32_16x16x32_bf16(af[mt], bfl[nt], acc[mt][nt], 0, 0, 0);
                }
            }
    }

    // epilogue: C row = quad*4+reg, col = l16 within each 16x16 tile
    #pragma unroll
    for (int nt = 0; nt < 2; ++nt) {
        int col = n0 + wn * 32 + nt * 16 + l16;
        float bcol = bias[col];
        #pragma unroll
        for (int mt = 0; mt < 4; ++mt) {
            #pragma unroll
            for (int reg = 0; reg < 4; ++reg) {
                int row = m0 + wm * 64 + mt * 16 + quad * 4 + reg;
                float v = acc[mt][nt][reg] + bcol;
                if (OUT_BF16) Cb[(size_t)row * N + col] = f2bf(v);
                else          Cf[(size_t)row * N + col] = v;
            }
        }
    }
}

// ---------------------------------------------------------------------------
// vpb [B,S,D] bf16 -> vpT [B,H,64,S] bf16 (per-head transpose)
// ---------------------------------------------------------------------------
__global__ __launch_bounds__(256) void transpose_v(
    const unsigned short* __restrict__ vpb, unsigned short* __restrict__ vpT)
{
    __shared__ unsigned short t[64][72];
    int bid = blockIdx.x;
    int st = bid & 15, h = (bid >> 4) & 15, b = bid >> 8;
    int s0 = st << 6;
    int tid = threadIdx.x;
    #pragma unroll
    for (int s = tid; s < 512; s += 256) {
        int r = s >> 3, p = (s & 7) << 3;
        *(ushort8*)&t[r][p] = *(const ushort8*)&vpb[(size_t)(b * SEQ + s0 + r) * DIM + h * HD + p];
    }
    __syncthreads();
    #pragma unroll
    for (int s = tid; s < 512; s += 256) {
        int dd = s >> 3, p = (s & 7) << 3;
        unsigned short tmp[8];
        #pragma unroll
        for (int j = 0; j < 8; ++j) tmp[j] = t[p + j][dd];
        *(ushort8*)&vpT[((size_t)((b * NH + h) * 64 + dd)) * SEQ + s0 + p] = *(ushort8*)tmp;
    }
}

// ---------------------------------------------------------------------------
// K'' trig table: Kt[j, c] = c<32 ? sin(j*dt_c) : cos(j*dt_{c-32}), split hi/lo
// ---------------------------------------------------------------------------
__global__ void prep_ktrig(unsigned short* __restrict__ Kth,
                           unsigned short* __restrict__ Ktl) {
    int idx = blockIdx.x * 256 + threadIdx.x;   // [0, SEQ*64)
    int j = idx >> 6;
    int c = idx & 63;
    int i = c & 31;
    float dt = __expf((float)i * DT_CONST);
    float ang = (float)j * dt;
    float val = (c < 32) ? sinf(ang) : cosf(ang);
    unsigned short hi, lo;
    bfsplit(val, hi, lo);
    Kth[idx] = hi;
    Ktl[idx] = lo;
}

// ---------------------------------------------------------------------------
// Q'' prep: Qh/Ql [B,H,S,128] bf16 hi/lo.
// d<64: projected q head.  d in [64,96): sin-coef.  d in [96,128): cos-coef.
// ---------------------------------------------------------------------------
__global__ __launch_bounds__(256) void prep_q(
    const float* __restrict__ qp,      // [B,S,D]
    const float* __restrict__ v_bias,  // [H,64]
    unsigned short* __restrict__ Qh,
    unsigned short* __restrict__ Ql)
{
    int tid = threadIdx.x;
    int sub = tid >> 7;            // 0..1
    int d = tid & 127;
    int row = blockIdx.x * 2 + sub;    // [0, B*H*S)
    int b = row >> 14;
    int h = (row >> 10) & 15;
    int q = row & 1023;

    float val;
    if (d < 64) {
        val = qp[((size_t)(b * SEQ + q)) * DIM + h * HD + d];
    } else {
        int i = d & 31;
        float qs = qp[((size_t)(b * SEQ + q)) * DIM + h * HD + i];
        float qc = qp[((size_t)(b * SEQ + q)) * DIM + h * HD + 32 + i];
        float vs = v_bias[h * HD + i];
        float vc = v_bias[h * HD + 32 + i];
        float u = qs + vs;
        float w = qc + vc;
        float dt = __expf((float)i * DT_CONST);
        float ang = (float)q * dt;
        float Cq = cosf(ang), Sq = sinf(ang);
        val = (d < 96) ? (u * Cq + w * Sq) : (w * Cq - u * Sq);
    }
    unsigned short hi, lo;
    bfsplit(val, hi, lo);
    size_t o = ((size_t)row) * 128 + d;
    Qh[o] = hi;
    Ql[o] = lo;
}

// ---------------------------------------------------------------------------
// Flash attention with MFMA. Block = 256 thr (4 waves), 64 q-rows, one (b,h).
// All staged inputs are pre-converted bf16 -> staging is pure vector copy.
// ---------------------------------------------------------------------------
#define LDK 136   // K'' / Q'' LDS row stride (shorts); 272B = 17*16B
#define LDV 72    // Vt / Ps row stride (shorts); 144B = 9*16B

__global__ __launch_bounds__(256) void attn_mfma(
    const unsigned short* __restrict__ Kh,   // [B,S,D] bf16 hi
    const unsigned short* __restrict__ Kl,   // [B,S,D] bf16 lo
    const unsigned short* __restrict__ vpT,  // [B,H,64,S] bf16
    const unsigned short* __restrict__ Qh,   // [B,H,S,128]
    const unsigned short* __restrict__ Ql,
    const unsigned short* __restrict__ Kth,  // [S,64]
    const unsigned short* __restrict__ Ktl,
    unsigned short* __restrict__ xab)        // [B,S,D] bf16
{
    __shared__ unsigned short Ksh[64][LDK];
    __shared__ unsigned short Ksl[64][LDK];
    __shared__ unsigned short Vt[64][LDV];
    __shared__ unsigned short Ps[64][LDV];

    int tid = threadIdx.x;
    int w = tid >> 6;
    int lane = tid & 63;
    int l16 = lane & 15;
    int quad = lane >> 4;

    int bid = blockIdx.x;
    int qt = bid & 15;
    int h = (bid >> 4) & 15;
    int b = bid >> 8;
    int q0 = qt << 6;

    // ---- stage Q'' into Ksh/Ksl, pull A-fragments to registers ----
    {
        const unsigned short* gq = Qh + (((size_t)(b * NH + h)) * SEQ + q0) * 128;
        const unsigned short* gl = Ql + (((size_t)(b * NH + h)) * SEQ + q0) * 128;
        #pragma unroll
        for (int c = tid; c < 1024; c += 256) {
            int r = c >> 4, s8 = (c & 15) << 3;
            *(ushort8*)&Ksh[r][s8] = *(const ushort8*)&gq[r * 128 + s8];
            *(ushort8*)&Ksl[r][s8] = *(const ushort8*)&gl[r * 128 + s8];
        }
    }
    __syncthreads();

    bf16x8 ah[4], al[4];
    #pragma unroll
    for (int c = 0; c < 4; ++c) {
        ah[c] = *(const bf16x8*)&Ksh[w * 16 + l16][c * 32 + quad * 8];
        al[c] = *(const bf16x8*)&Ksl[w * 16 + l16][c * 32 + quad * 8];
    }
    __syncthreads();

    f32x4 oacc[4];
    #pragma unroll
    for (int nb = 0; nb < 4; ++nb) oacc[nb] = (f32x4){0.f, 0.f, 0.f, 0.f};
    float mval[4] = {-INFINITY, -INFINITY, -INFINITY, -INFINITY};
    float lval[4] = {0.f, 0.f, 0.f, 0.f};

    for (int jt = 0; jt < 16; ++jt) {
        int j0 = jt << 6;

        // ---- stage K''(hi/lo) + trig + V tiles: pure ushort8 copies ----
        #pragma unroll
        for (int s = tid; s < 512; s += 256) {
            int r = s >> 3, p = (s & 7) << 3;
            size_t go = (size_t)(b * SEQ + j0 + r) * DIM + h * HD + p;
            *(ushort8*)&Ksh[r][p] = *(const ushort8*)&Kh[go];
            *(ushort8*)&Ksl[r][p] = *(const ushort8*)&Kl[go];
            size_t to = (size_t)(j0 + r) * 64 + p;
            *(ushort8*)&Ksh[r][64 + p] = *(const ushort8*)&Kth[to];
            *(ushort8*)&Ksl[r][64 + p] = *(const ushort8*)&Ktl[to];
            size_t vo = ((size_t)((b * NH + h) * 64 + r)) * SEQ + j0 + p;
            *(ushort8*)&Vt[r][p] = *(const ushort8*)&vpT[vo];
        }
        __syncthreads();

        // ---- QK^T: S[16 x 64] per wave, split-bf16 ----
        f32x4 sacc[4];
        #pragma unroll
        for (int nb = 0; nb < 4; ++nb) {
            sacc[nb] = (f32x4){0.f, 0.f, 0.f, 0.f};
            #pragma unroll
            for (int c = 0; c < 4; ++c) {
                bf16x8 bh = *(const bf16x8*)&Ksh[nb * 16 + l16][c * 32 + quad * 8];
                bf16x8 bl = *(const bf16x8*)&Ksl[nb * 16 + l16][c * 32 + quad * 8];
                sacc[nb] = __builtin_amdgcn_mfma_f32_16x16x32_bf16(ah[c], bh, sacc[nb], 0, 0, 0);
                sacc[nb] = __builtin_amdgcn_mfma_f32_16x16x32_bf16(al[c], bh, sacc[nb], 0, 0, 0);
                sacc[nb] = __builtin_amdgcn_mfma_f32_16x16x32_bf16(ah[c], bl, sacc[nb], 0, 0, 0);
            }
        }

        // ---- online softmax (rows = quad*4 + reg, cols across 16 lanes) ----
        #pragma unroll
        for (int r = 0; r < 4; ++r) {
            float v = fmaxf(fmaxf(sacc[0][r], sacc[1][r]), fmaxf(sacc[2][r], sacc[3][r]));
            #pragma unroll
            for (int mask = 1; mask < 16; mask <<= 1)
                v = fmaxf(v, __shfl_xor(v, mask, 64));
            float mnew = fmaxf(mval[r], v);
            float alpha = __expf(mval[r] - mnew);
            float p0 = __expf(sacc[0][r] - mnew);
            float p1 = __expf(sacc[1][r] - mnew);
            float p2 = __expf(sacc[2][r] - mnew);
            float p3 = __expf(sacc[3][r] - mnew);
            float rs = (p0 + p1) + (p2 + p3);
            #pragma unroll
            for (int mask = 1; mask < 16; mask <<= 1)
                rs += __shfl_xor(rs, mask, 64);
            lval[r] = lval[r] * alpha + rs;
            mval[r] = mnew;
            int prow = w * 16 + quad * 4 + r;
            Ps[prow][0 * 16 + l16] = f2bf(p0);
            Ps[prow][1 * 16 + l16] = f2bf(p1);
            Ps[prow][2 * 16 + l16] = f2bf(p2);
            Ps[prow][3 * 16 + l16] = f2bf(p3);
            oacc[0][r] *= alpha;
            oacc[1][r] *= alpha;
            oacc[2][r] *= alpha;
            oacc[3][r] *= alpha;
        }
        // each wave reads back only its own 16 Ps rows; Vt stable since barrier

        // ---- PV: O[16 x 64] += P[16 x 64] * V[64 x 64] ----
        #pragma unroll
        for (int nb = 0; nb < 4; ++nb) {
            #pragma unroll
            for (int kc = 0; kc < 2; ++kc) {
                bf16x8 a = *(const bf16x8*)&Ps[w * 16 + l16][kc * 32 + quad * 8];
                bf16x8 bv = *(const bf16x8*)&Vt[nb * 16 + l16][kc * 32 + quad * 8];
                oacc[nb] = __builtin_amdgcn_mfma_f32_16x16x32_bf16(a, bv, oacc[nb], 0, 0, 0);
            }
        }
        __syncthreads();
    }

    // ---- epilogue: divide by l, write xa bf16 [B,S,H*dv] ----
    #pragma unroll
    for (int r = 0; r < 4; ++r) {
        float inv = 1.f / lval[r];
        int qrow = q0 + w * 16 + quad * 4 + r;
        #pragma unroll
        for (int nb = 0; nb < 4; ++nb) {
            xab[((size_t)(b * SEQ + qrow)) * DIM + h * HD + nb * 16 + l16] = f2bf(oacc[nb][r] * inv);
        }
    }
}

// ---------------------------------------------------------------------------
extern "C" void kernel_launch(void* const* d_in, const int* in_sizes, int n_in,
                              void* d_out, int out_size, void* d_ws, size_t ws_size,
                              hipStream_t stream) {
    const float* query  = (const float*)d_in[0];
    const float* key    = (const float*)d_in[1];
    const float* value  = (const float*)d_in[2];
    // d_in[3]: mask — unused (reference softmax is unmasked)
    const float* Wq     = (const float*)d_in[4];
    const float* bq     = (const float*)d_in[5];
    const float* Wv     = (const float*)d_in[6];
    const float* bv     = (const float*)d_in[7];
    const float* Wo     = (const float*)d_in[8];
    const float* bo     = (const float*)d_in[9];
    const float* v_bias = (const float*)d_in[10];

    float* out = (float*)d_out;
    char* base = (char*)d_ws;
    const size_t MB = 1024 * 1024;

    // Region A (8 MB): qp f32 -> later xa bf16 (4) + vpT bf16 (4)
    float* qp = (float*)base;
    unsigned short* xab = (unsigned short*)base;
    unsigned short* vpT = (unsigned short*)(base + 4 * MB);
    // Region B (8 MB): query hi/lo -> later key hi/lo
    unsigned short* Ash = (unsigned short*)(base + 8 * MB);
    unsigned short* Asl = (unsigned short*)(base + 12 * MB);
    // Region C (4 MB): Wq hi/lo -> later Wv_h + Wo_h
    unsigned short* Wqh = (unsigned short*)(base + 16 * MB);
    unsigned short* Wql = (unsigned short*)(base + 18 * MB);
    unsigned short* Wvh = (unsigned short*)(base + 16 * MB);
    unsigned short* Woh = (unsigned short*)(base + 18 * MB);
    // Region D (4 MB): value_h
    unsigned short* Valh = (unsigned short*)(base + 20 * MB);
    // Region E (4 MB): vp bf16
    unsigned short* vpb = (unsigned short*)(base + 24 * MB);
    // Region F (16 MB): Qh, Ql
    unsigned short* Qh = (unsigned short*)(base + 28 * MB);
    unsigned short* Ql = (unsigned short*)(base + 36 * MB);
    // Region G: trig tables
    unsigned short* Kth = (unsigned short*)(base + 44 * MB);
    unsigned short* Ktl = Kth + (size_t)SEQ * 64;

    const int M = NB * SEQ, N = DIM, K = DIM;
    dim3 ggrid(N / 64, M / 128);

    // q projection (split bf16)
    conv_split<<<M * K / 1024, 256, 0, stream>>>(query, Ash, Asl, M * K);
    conv_split<<<N * K / 1024, 256, 0, stream>>>(Wq, Wqh, Wql, N * K);
    gemm_mfma<true, false><<<ggrid, 256, 0, stream>>>(Ash, Asl, Wqh, Wql, bq, qp, nullptr, M, N, K);
    prep_q<<<NB * NH * SEQ / 2, 256, 0, stream>>>(qp, v_bias, Qh, Ql);

    // v projection (plain bf16, bf16 out) + transpose
    conv_plain<<<M * K / 1024, 256, 0, stream>>>(value, Valh, M * K);
    conv_plain<<<N * K / 1024, 256, 0, stream>>>(Wv, Wvh, N * K);
    conv_plain<<<N * K / 1024, 256, 0, stream>>>(Wo, Woh, N * K);
    gemm_mfma<false, true><<<ggrid, 256, 0, stream>>>(Valh, nullptr, Wvh, nullptr, bv, nullptr, vpb, M, N, K);
    transpose_v<<<NB * NH * (SEQ / 64), 256, 0, stream>>>(vpb, vpT);

    // key split + trig tables
    conv_split<<<M * K / 1024, 256, 0, stream>>>(key, Ash, Asl, M * K);  // reuse as Kh/Kl
    prep_ktrig<<<SEQ * 64 / 256, 256, 0, stream>>>(Kth, Ktl);

    // attention
    attn_mfma<<<NB * NH * (SEQ / 64), 256, 0, stream>>>(Ash, Asl, vpT, Qh, Ql, Kth, Ktl, xab);

    // output projection (plain bf16, f32 out)
    gemm_mfma<false, false><<<ggrid, 256, 0, stream>>>(xab, nullptr, Woh, nullptr, bo, out, nullptr, M, N, K);
}

// Round 5
// 239.864 us; speedup vs baseline: 15.6079x; 1.0300x over previous
//
#include <hip/hip_runtime.h>
#include <math.h>

#define SEQ 1024
#define DIM 1024
#define NH 16
#define HD 64
#define NB 2

typedef __attribute__((ext_vector_type(8))) short bf16x8;
typedef __attribute__((ext_vector_type(4))) float f32x4;
typedef __attribute__((ext_vector_type(8))) unsigned short ushort8;
typedef __attribute__((ext_vector_type(4))) unsigned short ushort4v;

#define DT_CONST (-0.2971077539347156f)   // -ln(10000)/31

__device__ __forceinline__ unsigned short f2bf(float x) {
    unsigned u = __float_as_uint(x);
    return (unsigned short)((u + 0x7fffu + ((u >> 16) & 1u)) >> 16);
}
__device__ __forceinline__ float bf2f(unsigned short h) {
    return __uint_as_float(((unsigned)h) << 16);
}
__device__ __forceinline__ void bfsplit(float x, unsigned short& hi, unsigned short& lo) {
    hi = f2bf(x);
    lo = f2bf(x - bf2f(hi));
}

// ---------------------------------------------------------------------------
// conv_split: f32 -> bf16 hi+lo (for key, feeding attn staging)
// ---------------------------------------------------------------------------
__global__ __launch_bounds__(256) void conv_split(
    const float* __restrict__ x, unsigned short* __restrict__ h,
    unsigned short* __restrict__ l, int n)
{
    int i = (blockIdx.x * 256 + threadIdx.x) * 4;
    if (i >= n) return;
    float4 v = *(const float4*)&x[i];
    unsigned short hx, lx, hy, ly, hz, lz, hw, lw;
    bfsplit(v.x, hx, lx); bfsplit(v.y, hy, ly);
    bfsplit(v.z, hz, lz); bfsplit(v.w, hw, lw);
    ushort4v hv, lv;
    hv.x = hx; hv.y = hy; hv.z = hz; hv.w = hw;
    lv.x = lx; lv.y = ly; lv.z = lz; lv.w = lw;
    *(ushort4v*)&h[i] = hv;
    *(ushort4v*)&l[i] = lv;
}

// ---------------------------------------------------------------------------
// Fused q-proj + v-proj GEMM. grid (N/64, M/128, 2); z=0: q (split-bf16,
// f32 out), z=1: v (plain bf16, bf16 out TRANSPOSED per head into vpT).
// Reads f32 A/W directly, converts during staging (GEMM VALU is idle).
// Tile 128x64, BK=32, 4 waves (2x2), each wave 64x32 (4x2 16x16 tiles).
// ---------------------------------------------------------------------------
__global__ __launch_bounds__(256) void qv_gemm(
    const float* __restrict__ query, const float* __restrict__ Wq,
    const float* __restrict__ bq,
    const float* __restrict__ value, const float* __restrict__ Wv,
    const float* __restrict__ bv,
    float* __restrict__ qp,          // [M,N] f32
    unsigned short* __restrict__ vpT) // [B,H,64,SEQ] bf16
{
    __shared__ __align__(16) unsigned short smem[12288];   // 24 KB
    unsigned short (*sAh)[32] = (unsigned short(*)[32])smem;          // 128x32
    unsigned short (*sAl)[32] = (unsigned short(*)[32])(smem + 4096); // 128x32
    unsigned short (*sWh)[32] = (unsigned short(*)[32])(smem + 8192); // 64x32
    unsigned short (*sWl)[32] = (unsigned short(*)[32])(smem + 10240);// 64x32

    const int K = DIM, N = DIM;
    bool isq = (blockIdx.z == 0);
    const float* A = isq ? query : value;
    const float* W = isq ? Wq : Wv;

    int tid = threadIdx.x;
    int lane = tid & 63;
    int w = tid >> 6;
    int l16 = lane & 15, quad = lane >> 4;
    int wm = w & 1, wn = w >> 1;
    int m0 = blockIdx.y * 128, n0 = blockIdx.x * 64;

    int arA = tid >> 3;          // 0..31 (A rows arA, +32, +64, +96)
    int ac4 = (tid & 7) << 2;    // f32 col offset 0,4,..,28

    f32x4 acc[4][2];
    #pragma unroll
    for (int mt = 0; mt < 4; ++mt)
        #pragma unroll
        for (int nt = 0; nt < 2; ++nt)
            acc[mt][nt] = (f32x4){0.f, 0.f, 0.f, 0.f};

    for (int kk = 0; kk < K; kk += 32) {
        float4 a4[4], w4[2];
        #pragma unroll
        for (int i = 0; i < 4; ++i)
            a4[i] = *(const float4*)&A[(size_t)(m0 + arA + i * 32) * K + kk + ac4];
        #pragma unroll
        for (int i = 0; i < 2; ++i)
            w4[i] = *(const float4*)&W[(size_t)(n0 + arA + i * 32) * K + kk + ac4];
        __syncthreads();
        if (isq) {
            #pragma unroll
            for (int i = 0; i < 4; ++i) {
                unsigned short h0,l0,h1,l1,h2,l2,h3,l3;
                bfsplit(a4[i].x,h0,l0); bfsplit(a4[i].y,h1,l1);
                bfsplit(a4[i].z,h2,l2); bfsplit(a4[i].w,h3,l3);
                ushort4v hv, lv; hv.x=h0;hv.y=h1;hv.z=h2;hv.w=h3; lv.x=l0;lv.y=l1;lv.z=l2;lv.w=l3;
                *(ushort4v*)&sAh[arA + i * 32][ac4] = hv;
                *(ushort4v*)&sAl[arA + i * 32][ac4] = lv;
            }
            #pragma unroll
            for (int i = 0; i < 2; ++i) {
                unsigned short h0,l0,h1,l1,h2,l2,h3,l3;
                bfsplit(w4[i].x,h0,l0); bfsplit(w4[i].y,h1,l1);
                bfsplit(w4[i].z,h2,l2); bfsplit(w4[i].w,h3,l3);
                ushort4v hv, lv; hv.x=h0;hv.y=h1;hv.z=h2;hv.w=h3; lv.x=l0;lv.y=l1;lv.z=l2;lv.w=l3;
                *(ushort4v*)&sWh[arA + i * 32][ac4] = hv;
                *(ushort4v*)&sWl[arA + i * 32][ac4] = lv;
            }
        } else {
            #pragma unroll
            for (int i = 0; i < 4; ++i) {
                ushort4v hv;
                hv.x = f2bf(a4[i].x); hv.y = f2bf(a4[i].y);
                hv.z = f2bf(a4[i].z); hv.w = f2bf(a4[i].w);
                *(ushort4v*)&sAh[arA + i * 32][ac4] = hv;
            }
            #pragma unroll
            for (int i = 0; i < 2; ++i) {
                ushort4v hv;
                hv.x = f2bf(w4[i].x); hv.y = f2bf(w4[i].y);
                hv.z = f2bf(w4[i].z); hv.w = f2bf(w4[i].w);
                *(ushort4v*)&sWh[arA + i * 32][ac4] = hv;
            }
        }
        __syncthreads();

        bf16x8 af[4], bf[2], afl[4], bfl[2];
        #pragma unroll
        for (int mt = 0; mt < 4; ++mt) {
            af[mt] = *(const bf16x8*)&sAh[wm * 64 + mt * 16 + l16][quad * 8];
            if (isq) afl[mt] = *(const bf16x8*)&sAl[wm * 64 + mt * 16 + l16][quad * 8];
        }
        #pragma unroll
        for (int nt = 0; nt < 2; ++nt) {
            bf[nt] = *(const bf16x8*)&sWh[wn * 32 + nt * 16 + l16][quad * 8];
            if (isq) bfl[nt] = *(const bf16x8*)&sWl[wn * 32 + nt * 16 + l16][quad * 8];
        }
        #pragma unroll
        for (int mt = 0; mt < 4; ++mt)
            #pragma unroll
            for (int nt = 0; nt < 2; ++nt) {
                acc[mt][nt] = __builtin_amdgcn_mfma_f32_16x16x32_bf16(af[mt], bf[nt], acc[mt][nt], 0, 0, 0);
                if (isq) {
                    acc[mt][nt] = __builtin_amdgcn_mfma_f32_16x16x32_bf16(afl[mt], bf[nt], acc[mt][nt], 0, 0, 0);
                    acc[mt][nt] = __builtin_amdgcn_mfma_f32_16x16x32_bf16(af[mt], bfl[nt], acc[mt][nt], 0, 0, 0);
                }
            }
    }

    if (isq) {
        const float* bias = bq;
        #pragma unroll
        for (int nt = 0; nt < 2; ++nt) {
            int col = n0 + wn * 32 + nt * 16 + l16;
            float bcol = bias[col];
            #pragma unroll
            for (int mt = 0; mt < 4; ++mt)
                #pragma unroll
                for (int reg = 0; reg < 4; ++reg) {
                    int row = m0 + wm * 64 + mt * 16 + quad * 4 + reg;
                    qp[(size_t)row * N + col] = acc[mt][nt][reg] + bcol;
                }
        }
    } else {
        // transposed epilogue: tile is [128 s] x [64 dd] -> vpT[b,h,dd,s]
        __syncthreads();
        unsigned short* tb = smem;   // [64][136] = 8704 ushorts
        #pragma unroll
        for (int nt = 0; nt < 2; ++nt) {
            int col = wn * 32 + nt * 16 + l16;          // dd 0..63
            float bcol = bv[n0 + col];
            #pragma unroll
            for (int mt = 0; mt < 4; ++mt)
                #pragma unroll
                for (int reg = 0; reg < 4; ++reg) {
                    int row = wm * 64 + mt * 16 + quad * 4 + reg;   // s-in-tile
                    tb[col * 136 + row] = f2bf(acc[mt][nt][reg] + bcol);
                }
        }
        __syncthreads();
        int b = m0 >> 10;
        int s0 = m0 & (SEQ - 1);
        int h = blockIdx.x;
        #pragma unroll
        for (int i = tid; i < 1024; i += 256) {
            int dd = i >> 4, p = (i & 15) << 3;
            *(ushort8*)&vpT[((size_t)((b * NH + h) * 64 + dd)) * SEQ + s0 + p] =
                *(const ushort8*)&tb[dd * 136 + p];
        }
    }
}

// ---------------------------------------------------------------------------
// Output GEMM: out = xab(bf16) @ Wo^T(f32, converted in staging) + bo, f32 out
// ---------------------------------------------------------------------------
__global__ __launch_bounds__(256) void out_gemm(
    const unsigned short* __restrict__ Ab, const float* __restrict__ Wo,
    const float* __restrict__ bo, float* __restrict__ C)
{
    __shared__ unsigned short sA[128][32];
    __shared__ unsigned short sW[64][32];

    const int K = DIM, N = DIM;
    int tid = threadIdx.x;
    int lane = tid & 63;
    int w = tid >> 6;
    int l16 = lane & 15, quad = lane >> 4;
    int wm = w & 1, wn = w >> 1;
    int m0 = blockIdx.y * 128, n0 = blockIdx.x * 64;

    int ar = tid >> 2, ap = (tid & 3) << 3;   // A: ushort8 rows ar, ar+64
    int wr = tid >> 3, wc4 = (tid & 7) << 2;  // W: f32 rows wr, wr+32

    const unsigned short* pA0 = Ab + (size_t)(m0 + ar) * K + ap;
    const unsigned short* pA1 = pA0 + (size_t)64 * K;

    f32x4 acc[4][2];
    #pragma unroll
    for (int mt = 0; mt < 4; ++mt)
        #pragma unroll
        for (int nt = 0; nt < 2; ++nt)
            acc[mt][nt] = (f32x4){0.f, 0.f, 0.f, 0.f};

    for (int kk = 0; kk < K; kk += 32) {
        ushort8 a0 = *(const ushort8*)(pA0 + kk);
        ushort8 a1 = *(const ushort8*)(pA1 + kk);
        float4 w0 = *(const float4*)&Wo[(size_t)(n0 + wr) * K + kk + wc4];
        float4 w1 = *(const float4*)&Wo[(size_t)(n0 + wr + 32) * K + kk + wc4];
        __syncthreads();
        *(ushort8*)&sA[ar][ap] = a0;
        *(ushort8*)&sA[ar + 64][ap] = a1;
        ushort4v hv0, hv1;
        hv0.x = f2bf(w0.x); hv0.y = f2bf(w0.y); hv0.z = f2bf(w0.z); hv0.w = f2bf(w0.w);
        hv1.x = f2bf(w1.x); hv1.y = f2bf(w1.y); hv1.z = f2bf(w1.z); hv1.w = f2bf(w1.w);
        *(ushort4v*)&sW[wr][wc4] = hv0;
        *(ushort4v*)&sW[wr + 32][wc4] = hv1;
        __syncthreads();

        bf16x8 af[4], bf[2];
        #pragma unroll
        for (int mt = 0; mt < 4; ++mt)
            af[mt] = *(const bf16x8*)&sA[wm * 64 + mt * 16 + l16][quad * 8];
        #pragma unroll
        for (int nt = 0; nt < 2; ++nt)
            bf[nt] = *(const bf16x8*)&sW[wn * 32 + nt * 16 + l16][quad * 8];
        #pragma unroll
        for (int mt = 0; mt < 4; ++mt)
            #pragma unroll
            for (int nt = 0; nt < 2; ++nt)
                acc[mt][nt] = __builtin_amdgcn_mfma_f32_16x16x32_bf16(af[mt], bf[nt], acc[mt][nt], 0, 0, 0);
    }

    #pragma unroll
    for (int nt = 0; nt < 2; ++nt) {
        int col = n0 + wn * 32 + nt * 16 + l16;
        float bcol = bo[col];
        #pragma unroll
        for (int mt = 0; mt < 4; ++mt)
            #pragma unroll
            for (int reg = 0; reg < 4; ++reg) {
                int row = m0 + wm * 64 + mt * 16 + quad * 4 + reg;
                C[(size_t)row * N + col] = acc[mt][nt][reg] + bcol;
            }
    }
}

// ---------------------------------------------------------------------------
// K'' trig table: Kt[j, c] = c<32 ? sin(j*dt_c) : cos(j*dt_{c-32}), split hi/lo
// ---------------------------------------------------------------------------
__global__ void prep_ktrig(unsigned short* __restrict__ Kth,
                           unsigned short* __restrict__ Ktl) {
    int idx = blockIdx.x * 256 + threadIdx.x;   // [0, SEQ*64)
    int j = idx >> 6;
    int c = idx & 63;
    int i = c & 31;
    float dt = __expf((float)i * DT_CONST);
    float ang = (float)j * dt;
    float val = (c < 32) ? sinf(ang) : cosf(ang);
    unsigned short hi, lo;
    bfsplit(val, hi, lo);
    Kth[idx] = hi;
    Ktl[idx] = lo;
}

// ---------------------------------------------------------------------------
// Q'' prep: Qh/Ql [B,H,S,128] bf16 hi/lo.
// d<64: projected q head.  d in [64,96): sin-coef.  d in [96,128): cos-coef.
// ---------------------------------------------------------------------------
__global__ __launch_bounds__(256) void prep_q(
    const float* __restrict__ qp,      // [B,S,D]
    const float* __restrict__ v_bias,  // [H,64]
    unsigned short* __restrict__ Qh,
    unsigned short* __restrict__ Ql)
{
    int tid = threadIdx.x;
    int sub = tid >> 7;            // 0..1
    int d = tid & 127;
    int row = blockIdx.x * 2 + sub;    // [0, B*H*S)
    int b = row >> 14;
    int h = (row >> 10) & 15;
    int q = row & 1023;

    float val;
    if (d < 64) {
        val = qp[((size_t)(b * SEQ + q)) * DIM + h * HD + d];
    } else {
        int i = d & 31;
        float qs = qp[((size_t)(b * SEQ + q)) * DIM + h * HD + i];
        float qc = qp[((size_t)(b * SEQ + q)) * DIM + h * HD + 32 + i];
        float vs = v_bias[h * HD + i];
        float vc = v_bias[h * HD + 32 + i];
        float u = qs + vs;
        float w = qc + vc;
        float dt = __expf((float)i * DT_CONST);
        float ang = (float)q * dt;
        float Cq = cosf(ang), Sq = sinf(ang);
        val = (d < 96) ? (u * Cq + w * Sq) : (w * Cq - u * Sq);
    }
    unsigned short hi, lo;
    bfsplit(val, hi, lo);
    size_t o = ((size_t)row) * 128 + d;
    Qh[o] = hi;
    Ql[o] = lo;
}

// ---------------------------------------------------------------------------
// Flash attention. Block = 512 thr (8 waves), 128 q-rows, one (b,h).
// K/trig/V staged once per j-tile serve all 128 q-rows.
// ---------------------------------------------------------------------------
#define LDK 136   // 272B = 17*16B
#define LDV 72    // 144B = 9*16B

__global__ __launch_bounds__(512) void attn_mfma(
    const unsigned short* __restrict__ Kh,   // [B,S,D] bf16 hi
    const unsigned short* __restrict__ Kl,   // [B,S,D] bf16 lo
    const unsigned short* __restrict__ vpT,  // [B,H,64,S] bf16
    const unsigned short* __restrict__ Qh,   // [B,H,S,128]
    const unsigned short* __restrict__ Ql,
    const unsigned short* __restrict__ Kth,  // [S,64]
    const unsigned short* __restrict__ Ktl,
    unsigned short* __restrict__ xab)        // [B,S,D] bf16
{
    __shared__ unsigned short Ksh[64][LDK];
    __shared__ unsigned short Ksl[64][LDK];
    __shared__ unsigned short Vt[64][LDV];
    __shared__ unsigned short Ps[128][LDV];

    int tid = threadIdx.x;
    int w = tid >> 6;            // 0..7
    int lane = tid & 63;
    int l16 = lane & 15;
    int quad = lane >> 4;

    int bid = blockIdx.x;
    int qt = bid & 7;
    int h = (bid >> 3) & 15;
    int b = bid >> 7;
    int q0 = qt << 7;            // 128-row q tile

    // ---- stage Q'' in two 64-row halves; waves grab their A-fragments ----
    bf16x8 ah[4], al[4];
    #pragma unroll
    for (int half = 0; half < 2; ++half) {
        const unsigned short* gq = Qh + (((size_t)(b * NH + h)) * SEQ + q0 + half * 64) * 128;
        const unsigned short* gl = Ql + (((size_t)(b * NH + h)) * SEQ + q0 + half * 64) * 128;
        #pragma unroll
        for (int c = tid; c < 1024; c += 512) {
            int r = c >> 4, p = (c & 15) << 3;
            *(ushort8*)&Ksh[r][p] = *(const ushort8*)&gq[r * 128 + p];
            *(ushort8*)&Ksl[r][p] = *(const ushort8*)&gl[r * 128 + p];
        }
        __syncthreads();
        if ((w >> 2) == half) {
            #pragma unroll
            for (int c = 0; c < 4; ++c) {
                ah[c] = *(const bf16x8*)&Ksh[(w & 3) * 16 + l16][c * 32 + quad * 8];
                al[c] = *(const bf16x8*)&Ksl[(w & 3) * 16 + l16][c * 32 + quad * 8];
            }
        }
        __syncthreads();
    }

    f32x4 oacc[4];
    #pragma unroll
    for (int nb = 0; nb < 4; ++nb) oacc[nb] = (f32x4){0.f, 0.f, 0.f, 0.f};
    float mval[4] = {-INFINITY, -INFINITY, -INFINITY, -INFINITY};
    float lval[4] = {0.f, 0.f, 0.f, 0.f};

    for (int jt = 0; jt < 16; ++jt) {
        int j0 = jt << 6;

        // ---- stage K''(hi/lo) + trig + V tiles: pure ushort8 copies ----
        {
            int r = tid >> 3, p = (tid & 7) << 3;
            size_t go = (size_t)(b * SEQ + j0 + r) * DIM + h * HD + p;
            *(ushort8*)&Ksh[r][p] = *(const ushort8*)&Kh[go];
            *(ushort8*)&Ksl[r][p] = *(const ushort8*)&Kl[go];
            size_t to = (size_t)(j0 + r) * 64 + p;
            *(ushort8*)&Ksh[r][64 + p] = *(const ushort8*)&Kth[to];
            *(ushort8*)&Ksl[r][64 + p] = *(const ushort8*)&Ktl[to];
            size_t vo = ((size_t)((b * NH + h) * 64 + r)) * SEQ + j0 + p;
            *(ushort8*)&Vt[r][p] = *(const ushort8*)&vpT[vo];
        }
        __syncthreads();

        // ---- QK^T: S[16 x 64] per wave, split-bf16 ----
        f32x4 sacc[4];
        #pragma unroll
        for (int nb = 0; nb < 4; ++nb) {
            sacc[nb] = (f32x4){0.f, 0.f, 0.f, 0.f};
            #pragma unroll
            for (int c = 0; c < 4; ++c) {
                bf16x8 bh = *(const bf16x8*)&Ksh[nb * 16 + l16][c * 32 + quad * 8];
                bf16x8 bl = *(const bf16x8*)&Ksl[nb * 16 + l16][c * 32 + quad * 8];
                sacc[nb] = __builtin_amdgcn_mfma_f32_16x16x32_bf16(ah[c], bh, sacc[nb], 0, 0, 0);
                sacc[nb] = __builtin_amdgcn_mfma_f32_16x16x32_bf16(al[c], bh, sacc[nb], 0, 0, 0);
                sacc[nb] = __builtin_amdgcn_mfma_f32_16x16x32_bf16(ah[c], bl, sacc[nb], 0, 0, 0);
            }
        }

        // ---- online softmax (rows = quad*4 + reg, cols across 16 lanes) ----
        #pragma unroll
        for (int r = 0; r < 4; ++r) {
            float v = fmaxf(fmaxf(sacc[0][r], sacc[1][r]), fmaxf(sacc[2][r], sacc[3][r]));
            #pragma unroll
            for (int mask = 1; mask < 16; mask <<= 1)
                v = fmaxf(v, __shfl_xor(v, mask, 64));
            float mnew = fmaxf(mval[r], v);
            float alpha = __expf(mval[r] - mnew);
            float p0 = __expf(sacc[0][r] - mnew);
            float p1 = __expf(sacc[1][r] - mnew);
            float p2 = __expf(sacc[2][r] - mnew);
            float p3 = __expf(sacc[3][r] - mnew);
            float rs = (p0 + p1) + (p2 + p3);
            #pragma unroll
            for (int mask = 1; mask < 16; mask <<= 1)
                rs += __shfl_xor(rs, mask, 64);
            lval[r] = lval[r] * alpha + rs;
            mval[r] = mnew;
            int prow = w * 16 + quad * 4 + r;
            Ps[prow][0 * 16 + l16] = f2bf(p0);
            Ps[prow][1 * 16 + l16] = f2bf(p1);
            Ps[prow][2 * 16 + l16] = f2bf(p2);
            Ps[prow][3 * 16 + l16] = f2bf(p3);
            oacc[0][r] *= alpha;
            oacc[1][r] *= alpha;
            oacc[2][r] *= alpha;
            oacc[3][r] *= alpha;
        }
        // each wave reads back only its own 16 Ps rows; Vt stable since barrier

        // ---- PV: O[16 x 64] += P[16 x 64] * V[64 x 64] ----
        #pragma unroll
        for (int nb = 0; nb < 4; ++nb) {
            #pragma unroll
            for (int kc = 0; kc < 2; ++kc) {
                bf16x8 a = *(const bf16x8*)&Ps[w * 16 + l16][kc * 32 + quad * 8];
                bf16x8 bv = *(const bf16x8*)&Vt[nb * 16 + l16][kc * 32 + quad * 8];
                oacc[nb] = __builtin_amdgcn_mfma_f32_16x16x32_bf16(a, bv, oacc[nb], 0, 0, 0);
            }
        }
        __syncthreads();
    }

    // ---- epilogue: divide by l, write xa bf16 [B,S,H*dv] ----
    #pragma unroll
    for (int r = 0; r < 4; ++r) {
        float inv = 1.f / lval[r];
        int qrow = q0 + w * 16 + quad * 4 + r;
        #pragma unroll
        for (int nb = 0; nb < 4; ++nb) {
            xab[((size_t)(b * SEQ + qrow)) * DIM + h * HD + nb * 16 + l16] = f2bf(oacc[nb][r] * inv);
        }
    }
}

// ---------------------------------------------------------------------------
extern "C" void kernel_launch(void* const* d_in, const int* in_sizes, int n_in,
                              void* d_out, int out_size, void* d_ws, size_t ws_size,
                              hipStream_t stream) {
    const float* query  = (const float*)d_in[0];
    const float* key    = (const float*)d_in[1];
    const float* value  = (const float*)d_in[2];
    // d_in[3]: mask — unused (reference softmax is unmasked)
    const float* Wq     = (const float*)d_in[4];
    const float* bq     = (const float*)d_in[5];
    const float* Wv     = (const float*)d_in[6];
    const float* bv     = (const float*)d_in[7];
    const float* Wo     = (const float*)d_in[8];
    const float* bo     = (const float*)d_in[9];
    const float* v_bias = (const float*)d_in[10];

    float* out = (float*)d_out;
    char* base = (char*)d_ws;
    const size_t MB = 1024 * 1024;

    float* qp           = (float*)base;                     // 8 MB (reused as xab after prep_q)
    unsigned short* xab = (unsigned short*)base;            // 4 MB (aliases qp; attn runs after prep_q)
    unsigned short* vpT = (unsigned short*)(base + 8 * MB); // 4 MB
    unsigned short* Khs = (unsigned short*)(base + 12 * MB);// 4 MB
    unsigned short* Kls = (unsigned short*)(base + 16 * MB);// 4 MB
    unsigned short* Qh  = (unsigned short*)(base + 20 * MB);// 8 MB
    unsigned short* Ql  = (unsigned short*)(base + 28 * MB);// 8 MB
    unsigned short* Kth = (unsigned short*)(base + 36 * MB);// 128 KB
    unsigned short* Ktl = Kth + (size_t)SEQ * 64;           // 128 KB

    const int M = NB * SEQ;

    prep_ktrig<<<SEQ * 64 / 256, 256, 0, stream>>>(Kth, Ktl);
    conv_split<<<M * DIM / 1024, 256, 0, stream>>>(key, Khs, Kls, M * DIM);

    dim3 qvgrid(DIM / 64, M / 128, 2);
    qv_gemm<<<qvgrid, 256, 0, stream>>>(query, Wq, bq, value, Wv, bv, qp, vpT);

    prep_q<<<NB * NH * SEQ / 2, 256, 0, stream>>>(qp, v_bias, Qh, Ql);

    attn_mfma<<<NB * NH * (SEQ / 128), 512, 0, stream>>>(Khs, Kls, vpT, Qh, Ql, Kth, Ktl, xab);

    dim3 ogrid(DIM / 64, M / 128);
    out_gemm<<<ogrid, 256, 0, stream>>>(xab, Wo, bo, out);
}

// Round 6
// 207.659 us; speedup vs baseline: 18.0284x; 1.1551x over previous
//
#include <hip/hip_runtime.h>
#include <math.h>

#define SEQ 1024
#define DIM 1024
#define NH 16
#define HD 64
#define NB 2

typedef __attribute__((ext_vector_type(8))) short bf16x8;
typedef __attribute__((ext_vector_type(4))) float f32x4;
typedef __attribute__((ext_vector_type(8))) unsigned short ushort8;
typedef __attribute__((ext_vector_type(4))) unsigned short ushort4v;

#define DT_CONST (-0.2971077539347156f)   // -ln(10000)/31

__device__ __forceinline__ unsigned short f2bf(float x) {
    unsigned u = __float_as_uint(x);
    return (unsigned short)((u + 0x7fffu + ((u >> 16) & 1u)) >> 16);
}
__device__ __forceinline__ float bf2f(unsigned short h) {
    return __uint_as_float(((unsigned)h) << 16);
}
__device__ __forceinline__ void bfsplit(float x, unsigned short& hi, unsigned short& lo) {
    hi = f2bf(x);
    lo = f2bf(x - bf2f(hi));
}

// ---------------------------------------------------------------------------
// conv_split: f32 -> bf16 hi+lo (key, feeding attn staging)
// ---------------------------------------------------------------------------
__global__ __launch_bounds__(256) void conv_split(
    const float* __restrict__ x, unsigned short* __restrict__ h,
    unsigned short* __restrict__ l, int n)
{
    int i = (blockIdx.x * 256 + threadIdx.x) * 4;
    if (i >= n) return;
    float4 v = *(const float4*)&x[i];
    unsigned short hx, lx, hy, ly, hz, lz, hw, lw;
    bfsplit(v.x, hx, lx); bfsplit(v.y, hy, ly);
    bfsplit(v.z, hz, lz); bfsplit(v.w, hw, lw);
    ushort4v hv, lv;
    hv.x = hx; hv.y = hy; hv.z = hz; hv.w = hw;
    lv.x = lx; lv.y = ly; lv.z = lz; lv.w = lw;
    *(ushort4v*)&h[i] = hv;
    *(ushort4v*)&l[i] = lv;
}

// ---------------------------------------------------------------------------
// K'' trig table: Kt[j, c] = c<32 ? sin(j*dt_c) : cos(j*dt_{c-32}), hi/lo
// ---------------------------------------------------------------------------
__global__ void prep_ktrig(unsigned short* __restrict__ Kth,
                           unsigned short* __restrict__ Ktl) {
    int idx = blockIdx.x * 256 + threadIdx.x;
    int j = idx >> 6;
    int c = idx & 63;
    int i = c & 31;
    float dt = __expf((float)i * DT_CONST);
    float ang = (float)j * dt;
    float val = (c < 32) ? sinf(ang) : cosf(ang);
    unsigned short hi, lo;
    bfsplit(val, hi, lo);
    Kth[idx] = hi;
    Ktl[idx] = lo;
}

// ---------------------------------------------------------------------------
// Fused q-proj + v-proj GEMM. grid (16, 16, 2). z=0: q (split-bf16 MFMA,
// epilogue computes Q'' = [head | sin-coef | cos-coef] hi/lo directly).
// z=1: v (plain bf16, epilogue writes vpT[b,h,dd,s] with s k-PERMUTED
// within each 64-block: pos = (s&15)*4 + (s>>4), matching attn's Ps layout).
// Tile 128x64, BK=32, 4 waves; wave w: rows w*32..w*32+31, all 64 cols.
// Register-prefetch pipelined K-loop.
// ---------------------------------------------------------------------------
__global__ __launch_bounds__(256) void qv_gemm(
    const float* __restrict__ query, const float* __restrict__ Wq,
    const float* __restrict__ bq,
    const float* __restrict__ value, const float* __restrict__ Wv,
    const float* __restrict__ bv,
    const float* __restrict__ v_bias,
    unsigned short* __restrict__ Qh, unsigned short* __restrict__ Ql,
    unsigned short* __restrict__ vpT)
{
    __shared__ __align__(16) unsigned short smem[12288];   // 24 KB
    unsigned short (*sAh)[32] = (unsigned short(*)[32])smem;
    unsigned short (*sAl)[32] = (unsigned short(*)[32])(smem + 4096);
    unsigned short (*sWh)[32] = (unsigned short(*)[32])(smem + 8192);
    unsigned short (*sWl)[32] = (unsigned short(*)[32])(smem + 10240);

    const int K = DIM;
    bool isq = (blockIdx.z == 0);
    const float* A = isq ? query : value;
    const float* W = isq ? Wq : Wv;

    int tid = threadIdx.x;
    int lane = tid & 63;
    int w = tid >> 6;
    int l16 = lane & 15, quad = lane >> 4;
    int m0 = blockIdx.y * 128;
    int h = blockIdx.x;          // n0 = h*64
    int n0 = h * 64;

    int arA = tid >> 3;          // 0..31
    int ac4 = (tid & 7) << 2;

    f32x4 acc[2][4];
    #pragma unroll
    for (int mt = 0; mt < 2; ++mt)
        #pragma unroll
        for (int nt = 0; nt < 4; ++nt)
            acc[mt][nt] = (f32x4){0.f, 0.f, 0.f, 0.f};

    float4 a4[4], w4[2];
    #pragma unroll
    for (int i = 0; i < 4; ++i)
        a4[i] = *(const float4*)&A[(size_t)(m0 + arA + i * 32) * K + ac4];
    #pragma unroll
    for (int i = 0; i < 2; ++i)
        w4[i] = *(const float4*)&W[(size_t)(n0 + arA + i * 32) * K + ac4];

    for (int kk = 0; kk < K; kk += 32) {
        __syncthreads();
        if (isq) {
            #pragma unroll
            for (int i = 0; i < 4; ++i) {
                unsigned short h0,l0,h1,l1,h2,l2,h3,l3;
                bfsplit(a4[i].x,h0,l0); bfsplit(a4[i].y,h1,l1);
                bfsplit(a4[i].z,h2,l2); bfsplit(a4[i].w,h3,l3);
                ushort4v hv, lv; hv.x=h0;hv.y=h1;hv.z=h2;hv.w=h3; lv.x=l0;lv.y=l1;lv.z=l2;lv.w=l3;
                *(ushort4v*)&sAh[arA + i * 32][ac4] = hv;
                *(ushort4v*)&sAl[arA + i * 32][ac4] = lv;
            }
            #pragma unroll
            for (int i = 0; i < 2; ++i) {
                unsigned short h0,l0,h1,l1,h2,l2,h3,l3;
                bfsplit(w4[i].x,h0,l0); bfsplit(w4[i].y,h1,l1);
                bfsplit(w4[i].z,h2,l2); bfsplit(w4[i].w,h3,l3);
                ushort4v hv, lv; hv.x=h0;hv.y=h1;hv.z=h2;hv.w=h3; lv.x=l0;lv.y=l1;lv.z=l2;lv.w=l3;
                *(ushort4v*)&sWh[arA + i * 32][ac4] = hv;
                *(ushort4v*)&sWl[arA + i * 32][ac4] = lv;
            }
        } else {
            #pragma unroll
            for (int i = 0; i < 4; ++i) {
                ushort4v hv;
                hv.x = f2bf(a4[i].x); hv.y = f2bf(a4[i].y);
                hv.z = f2bf(a4[i].z); hv.w = f2bf(a4[i].w);
                *(ushort4v*)&sAh[arA + i * 32][ac4] = hv;
            }
            #pragma unroll
            for (int i = 0; i < 2; ++i) {
                ushort4v hv;
                hv.x = f2bf(w4[i].x); hv.y = f2bf(w4[i].y);
                hv.z = f2bf(w4[i].z); hv.w = f2bf(w4[i].w);
                *(ushort4v*)&sWh[arA + i * 32][ac4] = hv;
            }
        }
        if (kk + 32 < K) {
            #pragma unroll
            for (int i = 0; i < 4; ++i)
                a4[i] = *(const float4*)&A[(size_t)(m0 + arA + i * 32) * K + kk + 32 + ac4];
            #pragma unroll
            for (int i = 0; i < 2; ++i)
                w4[i] = *(const float4*)&W[(size_t)(n0 + arA + i * 32) * K + kk + 32 + ac4];
        }
        __syncthreads();

        bf16x8 af[2], bf[4], afl[2], bfl[4];
        #pragma unroll
        for (int mt = 0; mt < 2; ++mt) {
            af[mt] = *(const bf16x8*)&sAh[w * 32 + mt * 16 + l16][quad * 8];
            if (isq) afl[mt] = *(const bf16x8*)&sAl[w * 32 + mt * 16 + l16][quad * 8];
        }
        #pragma unroll
        for (int nt = 0; nt < 4; ++nt) {
            bf[nt] = *(const bf16x8*)&sWh[nt * 16 + l16][quad * 8];
            if (isq) bfl[nt] = *(const bf16x8*)&sWl[nt * 16 + l16][quad * 8];
        }
        #pragma unroll
        for (int mt = 0; mt < 2; ++mt)
            #pragma unroll
            for (int nt = 0; nt < 4; ++nt) {
                acc[mt][nt] = __builtin_amdgcn_mfma_f32_16x16x32_bf16(af[mt], bf[nt], acc[mt][nt], 0, 0, 0);
                if (isq) {
                    acc[mt][nt] = __builtin_amdgcn_mfma_f32_16x16x32_bf16(afl[mt], bf[nt], acc[mt][nt], 0, 0, 0);
                    acc[mt][nt] = __builtin_amdgcn_mfma_f32_16x16x32_bf16(af[mt], bfl[nt], acc[mt][nt], 0, 0, 0);
                }
            }
    }

    int b = m0 >> 10;

    if (isq) {
        // ---- fused Q'' epilogue: head vals + trig-combined coefs, hi/lo ----
        float bql[4], vbs[2], vbc[2], dti[2];
        #pragma unroll
        for (int nt = 0; nt < 4; ++nt) bql[nt] = bq[h * 64 + nt * 16 + l16];
        #pragma unroll
        for (int t = 0; t < 2; ++t) {
            vbs[t] = v_bias[h * 64 + t * 16 + l16];
            vbc[t] = v_bias[h * 64 + 32 + t * 16 + l16];
            dti[t] = __expf((float)(t * 16 + l16) * DT_CONST);
        }
        #pragma unroll
        for (int mt = 0; mt < 2; ++mt) {
            #pragma unroll
            for (int reg = 0; reg < 4; ++reg) {
                int row = m0 + w * 32 + mt * 16 + quad * 4 + reg;
                int q = row & (SEQ - 1);
                size_t qbase = ((size_t)(b * NH + h) * SEQ + q) * 128;
                float hv[4];
                #pragma unroll
                for (int nt = 0; nt < 4; ++nt) hv[nt] = acc[mt][nt][reg] + bql[nt];
                #pragma unroll
                for (int nt = 0; nt < 4; ++nt) {
                    unsigned short hi, lo;
                    bfsplit(hv[nt], hi, lo);
                    Qh[qbase + nt * 16 + l16] = hi;
                    Ql[qbase + nt * 16 + l16] = lo;
                }
                #pragma unroll
                for (int t = 0; t < 2; ++t) {
                    float u = hv[t] + vbs[t];
                    float wv = hv[t + 2] + vbc[t];
                    float ang = (float)q * dti[t];
                    float C = cosf(ang), S = sinf(ang);
                    float cs = u * C + wv * S;
                    float cc = wv * C - u * S;
                    unsigned short hi, lo;
                    bfsplit(cs, hi, lo);
                    Qh[qbase + 64 + t * 16 + l16] = hi;
                    Ql[qbase + 64 + t * 16 + l16] = lo;
                    bfsplit(cc, hi, lo);
                    Qh[qbase + 96 + t * 16 + l16] = hi;
                    Ql[qbase + 96 + t * 16 + l16] = lo;
                }
            }
        }
    } else {
        // ---- transposed + k-permuted epilogue into vpT[b,h,dd,s] ----
        __syncthreads();
        unsigned short* tb = smem;   // [64][136]
        #pragma unroll
        for (int nt = 0; nt < 4; ++nt) {
            int d = nt * 16 + l16;
            float bcol = bv[n0 + d];
            #pragma unroll
            for (int mt = 0; mt < 2; ++mt)
                #pragma unroll
                for (int reg = 0; reg < 4; ++reg) {
                    int srow = w * 32 + mt * 16 + quad * 4 + reg;
                    tb[d * 136 + srow] = f2bf(acc[mt][nt][reg] + bcol);
                }
        }
        __syncthreads();
        int s0 = m0 & (SEQ - 1);
        #pragma unroll
        for (int i = tid; i < 1024; i += 256) {
            int dd = i >> 4;
            int j16 = i & 15;
            int sb = j16 >> 3;
            int posl = (j16 & 7) << 3;
            unsigned short tmp[8];
            #pragma unroll
            for (int k = 0; k < 8; ++k) {
                int pos = posl + k;
                int sl = (pos >> 2) + (pos & 3) * 16;   // inverse permutation
                tmp[k] = tb[dd * 136 + sb * 64 + sl];
            }
            *(ushort8*)&vpT[((size_t)((b * NH + h) * 64 + dd)) * SEQ + s0 + sb * 64 + posl] =
                *(ushort8*)tmp;
        }
    }
}

// ---------------------------------------------------------------------------
// Output GEMM: out = xab(bf16) @ Wo^T + bo, f32 out. Prefetch-pipelined.
// ---------------------------------------------------------------------------
__global__ __launch_bounds__(256) void out_gemm(
    const unsigned short* __restrict__ Ab, const float* __restrict__ Wo,
    const float* __restrict__ bo, float* __restrict__ C)
{
    __shared__ unsigned short sA[128][32];
    __shared__ unsigned short sW[64][32];

    const int K = DIM, N = DIM;
    int tid = threadIdx.x;
    int lane = tid & 63;
    int w = tid >> 6;
    int l16 = lane & 15, quad = lane >> 4;
    int wm = w & 1, wn = w >> 1;
    int m0 = blockIdx.y * 128, n0 = blockIdx.x * 64;

    int ar = tid >> 2, ap = (tid & 3) << 3;
    int wr = tid >> 3, wc4 = (tid & 7) << 2;

    const unsigned short* pA0 = Ab + (size_t)(m0 + ar) * K + ap;
    const unsigned short* pA1 = pA0 + (size_t)64 * K;

    f32x4 acc[4][2];
    #pragma unroll
    for (int mt = 0; mt < 4; ++mt)
        #pragma unroll
        for (int nt = 0; nt < 2; ++nt)
            acc[mt][nt] = (f32x4){0.f, 0.f, 0.f, 0.f};

    ushort8 a0 = *(const ushort8*)(pA0);
    ushort8 a1 = *(const ushort8*)(pA1);
    float4 w0 = *(const float4*)&Wo[(size_t)(n0 + wr) * K + wc4];
    float4 w1 = *(const float4*)&Wo[(size_t)(n0 + wr + 32) * K + wc4];

    for (int kk = 0; kk < K; kk += 32) {
        __syncthreads();
        *(ushort8*)&sA[ar][ap] = a0;
        *(ushort8*)&sA[ar + 64][ap] = a1;
        ushort4v hv0, hv1;
        hv0.x = f2bf(w0.x); hv0.y = f2bf(w0.y); hv0.z = f2bf(w0.z); hv0.w = f2bf(w0.w);
        hv1.x = f2bf(w1.x); hv1.y = f2bf(w1.y); hv1.z = f2bf(w1.z); hv1.w = f2bf(w1.w);
        *(ushort4v*)&sW[wr][wc4] = hv0;
        *(ushort4v*)&sW[wr + 32][wc4] = hv1;
        if (kk + 32 < K) {
            a0 = *(const ushort8*)(pA0 + kk + 32);
            a1 = *(const ushort8*)(pA1 + kk + 32);
            w0 = *(const float4*)&Wo[(size_t)(n0 + wr) * K + kk + 32 + wc4];
            w1 = *(const float4*)&Wo[(size_t)(n0 + wr + 32) * K + kk + 32 + wc4];
        }
        __syncthreads();

        bf16x8 af[4], bf[2];
        #pragma unroll
        for (int mt = 0; mt < 4; ++mt)
            af[mt] = *(const bf16x8*)&sA[wm * 64 + mt * 16 + l16][quad * 8];
        #pragma unroll
        for (int nt = 0; nt < 2; ++nt)
            bf[nt] = *(const bf16x8*)&sW[wn * 32 + nt * 16 + l16][quad * 8];
        #pragma unroll
        for (int mt = 0; mt < 4; ++mt)
            #pragma unroll
            for (int nt = 0; nt < 2; ++nt)
                acc[mt][nt] = __builtin_amdgcn_mfma_f32_16x16x32_bf16(af[mt], bf[nt], acc[mt][nt], 0, 0, 0);
    }

    #pragma unroll
    for (int nt = 0; nt < 2; ++nt) {
        int col = n0 + wn * 32 + nt * 16 + l16;
        float bcol = bo[col];
        #pragma unroll
        for (int mt = 0; mt < 4; ++mt)
            #pragma unroll
            for (int reg = 0; reg < 4; ++reg) {
                int row = m0 + wm * 64 + mt * 16 + quad * 4 + reg;
                C[(size_t)row * N + col] = acc[mt][nt][reg] + bcol;
            }
    }
}

// ---------------------------------------------------------------------------
// Flash attention. Block = 256 thr (4 waves), 64 q-rows, one (b,h).
// Register-prefetch pipeline over j-tiles; P stored k-permuted (b64 writes)
// matching the permuted vpT.
// ---------------------------------------------------------------------------
#define LDK 136
#define LDV 72

__global__ __launch_bounds__(256) void attn_mfma(
    const unsigned short* __restrict__ Kh,
    const unsigned short* __restrict__ Kl,
    const unsigned short* __restrict__ vpT,  // [B,H,64,S] (s permuted per 64-blk)
    const unsigned short* __restrict__ Qh,   // [B,H,S,128]
    const unsigned short* __restrict__ Ql,
    const unsigned short* __restrict__ Kth,  // [S,64]
    const unsigned short* __restrict__ Ktl,
    unsigned short* __restrict__ xab)        // [B,S,D] bf16
{
    __shared__ unsigned short Ksh[64][LDK];
    __shared__ unsigned short Ksl[64][LDK];
    __shared__ unsigned short Vt[64][LDV];
    __shared__ unsigned short Ps[64][LDV];

    int tid = threadIdx.x;
    int w = tid >> 6;
    int lane = tid & 63;
    int l16 = lane & 15;
    int quad = lane >> 4;

    int bid = blockIdx.x;
    int qt = bid & 15;
    int h = (bid >> 4) & 15;
    int b = bid >> 8;
    int q0 = qt << 6;

    int sr0 = tid >> 3, sp0 = (tid & 7) << 3;          // stage slot 0 (rows 0..31)
    int sr1 = sr0 + 32;                                 // stage slot 1

    // ---- prefetch j-tile 0 ----
    ushort8 pKh0, pKl0, pTh0, pTl0, pV0, pKh1, pKl1, pTh1, pTl1, pV1;
    {
        size_t g0 = (size_t)(b * SEQ + sr0) * DIM + h * HD + sp0;
        size_t g1 = (size_t)(b * SEQ + sr1) * DIM + h * HD + sp0;
        pKh0 = *(const ushort8*)&Kh[g0]; pKl0 = *(const ushort8*)&Kl[g0];
        pKh1 = *(const ushort8*)&Kh[g1]; pKl1 = *(const ushort8*)&Kl[g1];
        size_t t0 = (size_t)sr0 * 64 + sp0, t1 = (size_t)sr1 * 64 + sp0;
        pTh0 = *(const ushort8*)&Kth[t0]; pTl0 = *(const ushort8*)&Ktl[t0];
        pTh1 = *(const ushort8*)&Kth[t1]; pTl1 = *(const ushort8*)&Ktl[t1];
        size_t v0 = ((size_t)((b * NH + h) * 64 + sr0)) * SEQ + sp0;
        size_t v1 = ((size_t)((b * NH + h) * 64 + sr1)) * SEQ + sp0;
        pV0 = *(const ushort8*)&vpT[v0]; pV1 = *(const ushort8*)&vpT[v1];
    }

    // ---- stage Q'' into Ksh/Ksl, pull A-fragments ----
    {
        const unsigned short* gq = Qh + (((size_t)(b * NH + h)) * SEQ + q0) * 128;
        const unsigned short* gl = Ql + (((size_t)(b * NH + h)) * SEQ + q0) * 128;
        #pragma unroll
        for (int c = tid; c < 1024; c += 256) {
            int r = c >> 4, p = (c & 15) << 3;
            *(ushort8*)&Ksh[r][p] = *(const ushort8*)&gq[r * 128 + p];
            *(ushort8*)&Ksl[r][p] = *(const ushort8*)&gl[r * 128 + p];
        }
    }
    __syncthreads();

    bf16x8 ah[4], al[4];
    #pragma unroll
    for (int c = 0; c < 4; ++c) {
        ah[c] = *(const bf16x8*)&Ksh[w * 16 + l16][c * 32 + quad * 8];
        al[c] = *(const bf16x8*)&Ksl[w * 16 + l16][c * 32 + quad * 8];
    }

    f32x4 oacc[4];
    #pragma unroll
    for (int nb = 0; nb < 4; ++nb) oacc[nb] = (f32x4){0.f, 0.f, 0.f, 0.f};
    float mval[4] = {-INFINITY, -INFINITY, -INFINITY, -INFINITY};
    float lval[4] = {0.f, 0.f, 0.f, 0.f};

    for (int jt = 0; jt < 16; ++jt) {
        __syncthreads();   // prev compute (and Q-frag reads) done with LDS
        *(ushort8*)&Ksh[sr0][sp0] = pKh0;  *(ushort8*)&Ksl[sr0][sp0] = pKl0;
        *(ushort8*)&Ksh[sr1][sp0] = pKh1;  *(ushort8*)&Ksl[sr1][sp0] = pKl1;
        *(ushort8*)&Ksh[sr0][64 + sp0] = pTh0; *(ushort8*)&Ksl[sr0][64 + sp0] = pTl0;
        *(ushort8*)&Ksh[sr1][64 + sp0] = pTh1; *(ushort8*)&Ksl[sr1][64 + sp0] = pTl1;
        *(ushort8*)&Vt[sr0][sp0] = pV0;    *(ushort8*)&Vt[sr1][sp0] = pV1;
        if (jt < 15) {
            int j0n = (jt + 1) << 6;
            size_t g0 = (size_t)(b * SEQ + j0n + sr0) * DIM + h * HD + sp0;
            size_t g1 = (size_t)(b * SEQ + j0n + sr1) * DIM + h * HD + sp0;
            pKh0 = *(const ushort8*)&Kh[g0]; pKl0 = *(const ushort8*)&Kl[g0];
            pKh1 = *(const ushort8*)&Kh[g1]; pKl1 = *(const ushort8*)&Kl[g1];
            size_t t0 = (size_t)(j0n + sr0) * 64 + sp0, t1 = (size_t)(j0n + sr1) * 64 + sp0;
            pTh0 = *(const ushort8*)&Kth[t0]; pTl0 = *(const ushort8*)&Ktl[t0];
            pTh1 = *(const ushort8*)&Kth[t1]; pTl1 = *(const ushort8*)&Ktl[t1];
            size_t v0 = ((size_t)((b * NH + h) * 64 + sr0)) * SEQ + j0n + sp0;
            size_t v1 = ((size_t)((b * NH + h) * 64 + sr1)) * SEQ + j0n + sp0;
            pV0 = *(const ushort8*)&vpT[v0]; pV1 = *(const ushort8*)&vpT[v1];
        }
        __syncthreads();

        // ---- QK^T: S[16 x 64] per wave, split-bf16 ----
        f32x4 sacc[4];
        #pragma unroll
        for (int nb = 0; nb < 4; ++nb) {
            sacc[nb] = (f32x4){0.f, 0.f, 0.f, 0.f};
            #pragma unroll
            for (int c = 0; c < 4; ++c) {
                bf16x8 bh = *(const bf16x8*)&Ksh[nb * 16 + l16][c * 32 + quad * 8];
                bf16x8 bl = *(const bf16x8*)&Ksl[nb * 16 + l16][c * 32 + quad * 8];
                sacc[nb] = __builtin_amdgcn_mfma_f32_16x16x32_bf16(ah[c], bh, sacc[nb], 0, 0, 0);
                sacc[nb] = __builtin_amdgcn_mfma_f32_16x16x32_bf16(al[c], bh, sacc[nb], 0, 0, 0);
                sacc[nb] = __builtin_amdgcn_mfma_f32_16x16x32_bf16(ah[c], bl, sacc[nb], 0, 0, 0);
            }
        }

        // ---- online softmax; P stored k-permuted: pos = l16*4 + c ----
        #pragma unroll
        for (int r = 0; r < 4; ++r) {
            float v = fmaxf(fmaxf(sacc[0][r], sacc[1][r]), fmaxf(sacc[2][r], sacc[3][r]));
            #pragma unroll
            for (int mask = 1; mask < 16; mask <<= 1)
                v = fmaxf(v, __shfl_xor(v, mask, 64));
            float mnew = fmaxf(mval[r], v);
            float alpha = __expf(mval[r] - mnew);
            float p0 = __expf(sacc[0][r] - mnew);
            float p1 = __expf(sacc[1][r] - mnew);
            float p2 = __expf(sacc[2][r] - mnew);
            float p3 = __expf(sacc[3][r] - mnew);
            float rs = (p0 + p1) + (p2 + p3);
            #pragma unroll
            for (int mask = 1; mask < 16; mask <<= 1)
                rs += __shfl_xor(rs, mask, 64);
            lval[r] = lval[r] * alpha + rs;
            mval[r] = mnew;
            int prow = w * 16 + quad * 4 + r;
            ushort4v pv4;
            pv4.x = f2bf(p0); pv4.y = f2bf(p1); pv4.z = f2bf(p2); pv4.w = f2bf(p3);
            *(ushort4v*)&Ps[prow][l16 * 4] = pv4;
            oacc[0][r] *= alpha;
            oacc[1][r] *= alpha;
            oacc[2][r] *= alpha;
            oacc[3][r] *= alpha;
        }
        // each wave reads back only its own 16 Ps rows; Vt stable since barrier

        // ---- PV: O[16 x 64] += P * V (k-space permuted consistently) ----
        #pragma unroll
        for (int nb = 0; nb < 4; ++nb) {
            #pragma unroll
            for (int kc = 0; kc < 2; ++kc) {
                bf16x8 a = *(const bf16x8*)&Ps[w * 16 + l16][kc * 32 + quad * 8];
                bf16x8 bv = *(const bf16x8*)&Vt[nb * 16 + l16][kc * 32 + quad * 8];
                oacc[nb] = __builtin_amdgcn_mfma_f32_16x16x32_bf16(a, bv, oacc[nb], 0, 0, 0);
            }
        }
    }

    // ---- epilogue ----
    #pragma unroll
    for (int r = 0; r < 4; ++r) {
        float inv = 1.f / lval[r];
        int qrow = q0 + w * 16 + quad * 4 + r;
        #pragma unroll
        for (int nb = 0; nb < 4; ++nb) {
            xab[((size_t)(b * SEQ + qrow)) * DIM + h * HD + nb * 16 + l16] = f2bf(oacc[nb][r] * inv);
        }
    }
}

// ---------------------------------------------------------------------------
extern "C" void kernel_launch(void* const* d_in, const int* in_sizes, int n_in,
                              void* d_out, int out_size, void* d_ws, size_t ws_size,
                              hipStream_t stream) {
    const float* query  = (const float*)d_in[0];
    const float* key    = (const float*)d_in[1];
    const float* value  = (const float*)d_in[2];
    // d_in[3]: mask — unused (reference softmax is unmasked)
    const float* Wq     = (const float*)d_in[4];
    const float* bq     = (const float*)d_in[5];
    const float* Wv     = (const float*)d_in[6];
    const float* bv     = (const float*)d_in[7];
    const float* Wo     = (const float*)d_in[8];
    const float* bo     = (const float*)d_in[9];
    const float* v_bias = (const float*)d_in[10];

    float* out = (float*)d_out;
    char* base = (char*)d_ws;
    const size_t MB = 1024 * 1024;

    unsigned short* xab = (unsigned short*)base;             // 4 MB
    unsigned short* vpT = (unsigned short*)(base + 4 * MB);  // 4 MB
    unsigned short* Khs = (unsigned short*)(base + 8 * MB);  // 4 MB
    unsigned short* Kls = (unsigned short*)(base + 12 * MB); // 4 MB
    unsigned short* Qh  = (unsigned short*)(base + 16 * MB); // 8 MB
    unsigned short* Ql  = (unsigned short*)(base + 24 * MB); // 8 MB
    unsigned short* Kth = (unsigned short*)(base + 32 * MB); // 128 KB
    unsigned short* Ktl = Kth + (size_t)SEQ * 64;            // 128 KB

    const int M = NB * SEQ;

    prep_ktrig<<<SEQ * 64 / 256, 256, 0, stream>>>(Kth, Ktl);
    conv_split<<<M * DIM / 1024, 256, 0, stream>>>(key, Khs, Kls, M * DIM);

    dim3 qvgrid(DIM / 64, M / 128, 2);
    qv_gemm<<<qvgrid, 256, 0, stream>>>(query, Wq, bq, value, Wv, bv, v_bias, Qh, Ql, vpT);

    attn_mfma<<<NB * NH * (SEQ / 64), 256, 0, stream>>>(Khs, Kls, vpT, Qh, Ql, Kth, Ktl, xab);

    dim3 ogrid(DIM / 64, M / 128);
    out_gemm<<<ogrid, 256, 0, stream>>>(xab, Wo, bo, out);
}

// Round 7
// 198.959 us; speedup vs baseline: 18.8167x; 1.0437x over previous
//
#include <hip/hip_runtime.h>
#include <math.h>

#define SEQ 1024
#define DIM 1024
#define NH 16
#define HD 64
#define NB 2

typedef __attribute__((ext_vector_type(8))) short bf16x8;
typedef __attribute__((ext_vector_type(4))) float f32x4;
typedef __attribute__((ext_vector_type(8))) unsigned short ushort8;
typedef __attribute__((ext_vector_type(4))) unsigned short ushort4v;

#define DT_CONST (-0.2971077539347156f)   // -ln(10000)/31

__device__ __forceinline__ unsigned short f2bf(float x) {
    unsigned u = __float_as_uint(x);
    return (unsigned short)((u + 0x7fffu + ((u >> 16) & 1u)) >> 16);
}
__device__ __forceinline__ float bf2f(unsigned short h) {
    return __uint_as_float(((unsigned)h) << 16);
}
__device__ __forceinline__ void bfsplit(float x, unsigned short& hi, unsigned short& lo) {
    hi = f2bf(x);
    lo = f2bf(x - bf2f(hi));
}

// ---------------------------------------------------------------------------
// One fused conversion kernel. grid (1024, 6):
//  y=0 query->split  y=1 key->split  y=2 value->plain (2M elems each)
//  y=3 Wq->split     y=4 Wv->plain   y=5 Wo->plain    (1M elems each)
// 8 elems/thread.
// ---------------------------------------------------------------------------
__device__ __forceinline__ void split8(const float* __restrict__ s,
                                       unsigned short* __restrict__ h,
                                       unsigned short* __restrict__ l, int i) {
    float4 v0 = *(const float4*)&s[i];
    float4 v1 = *(const float4*)&s[i + 4];
    float vs[8] = {v0.x, v0.y, v0.z, v0.w, v1.x, v1.y, v1.z, v1.w};
    ushort8 hv, lv;
    #pragma unroll
    for (int k = 0; k < 8; ++k) {
        unsigned short hi, lo;
        bfsplit(vs[k], hi, lo);
        hv[k] = hi; lv[k] = lo;
    }
    *(ushort8*)&h[i] = hv;
    *(ushort8*)&l[i] = lv;
}
__device__ __forceinline__ void plain8(const float* __restrict__ s,
                                       unsigned short* __restrict__ h, int i) {
    float4 v0 = *(const float4*)&s[i];
    float4 v1 = *(const float4*)&s[i + 4];
    float vs[8] = {v0.x, v0.y, v0.z, v0.w, v1.x, v1.y, v1.z, v1.w};
    ushort8 hv;
    #pragma unroll
    for (int k = 0; k < 8; ++k) hv[k] = f2bf(vs[k]);
    *(ushort8*)&h[i] = hv;
}

__global__ __launch_bounds__(256) void conv_all(
    const float* __restrict__ query, const float* __restrict__ key,
    const float* __restrict__ value, const float* __restrict__ Wq,
    const float* __restrict__ Wv, const float* __restrict__ Wo,
    unsigned short* __restrict__ Aqh, unsigned short* __restrict__ Aql,
    unsigned short* __restrict__ Khs, unsigned short* __restrict__ Kls,
    unsigned short* __restrict__ Vb,
    unsigned short* __restrict__ Wqh, unsigned short* __restrict__ Wql,
    unsigned short* __restrict__ Wvh, unsigned short* __restrict__ Woh)
{
    int i = (blockIdx.x * 256 + threadIdx.x) * 8;
    int r = blockIdx.y;
    const int NSMALL = DIM * DIM;
    if (r >= 3 && i >= NSMALL) return;
    switch (r) {
        case 0: split8(query, Aqh, Aql, i); break;
        case 1: split8(key,   Khs, Kls, i); break;
        case 2: plain8(value, Vb, i); break;
        case 3: split8(Wq, Wqh, Wql, i); break;
        case 4: plain8(Wv, Wvh, i); break;
        case 5: plain8(Wo, Woh, i); break;
    }
}

// ---------------------------------------------------------------------------
// K'' trig table: Kt[j, c] = c<32 ? sin(j*dt_c) : cos(j*dt_{c-32}), hi/lo
// ---------------------------------------------------------------------------
__global__ void prep_ktrig(unsigned short* __restrict__ Kth,
                           unsigned short* __restrict__ Ktl) {
    int idx = blockIdx.x * 256 + threadIdx.x;
    int j = idx >> 6;
    int c = idx & 63;
    int i = c & 31;
    float dt = __expf((float)i * DT_CONST);
    float ang = (float)j * dt;
    float val = (c < 32) ? sinf(ang) : cosf(ang);
    unsigned short hi, lo;
    bfsplit(val, hi, lo);
    Kth[idx] = hi;
    Ktl[idx] = lo;
}

// ---------------------------------------------------------------------------
// Fused q-proj + v-proj GEMM, pre-converted bf16 inputs (staging = copies).
// grid (16, 16, 2). z=0: q split-bf16 (3 MFMA/tile), fused Q'' epilogue.
// z=1: v plain, epilogue writes vpT[b,h,dd,s] s-permuted per 64-block.
// Tile 128x64, BK=32, 4 waves; wave w: rows w*32..+31, all 64 cols.
// ---------------------------------------------------------------------------
__global__ __launch_bounds__(256) void qv_gemm(
    const unsigned short* __restrict__ Aqh, const unsigned short* __restrict__ Aql,
    const unsigned short* __restrict__ Wqh, const unsigned short* __restrict__ Wql,
    const float* __restrict__ bq,
    const unsigned short* __restrict__ Vb, const unsigned short* __restrict__ Wvh,
    const float* __restrict__ bv,
    const float* __restrict__ v_bias,
    unsigned short* __restrict__ Qh, unsigned short* __restrict__ Ql,
    unsigned short* __restrict__ vpT)
{
    __shared__ __align__(16) unsigned short smem[12288];   // 24 KB
    unsigned short (*sAh)[32] = (unsigned short(*)[32])smem;
    unsigned short (*sAl)[32] = (unsigned short(*)[32])(smem + 4096);
    unsigned short (*sWh)[32] = (unsigned short(*)[32])(smem + 8192);
    unsigned short (*sWl)[32] = (unsigned short(*)[32])(smem + 10240);

    const int K = DIM;
    bool isq = (blockIdx.z == 0);

    int tid = threadIdx.x;
    int lane = tid & 63;
    int w = tid >> 6;
    int l16 = lane & 15, quad = lane >> 4;
    int m0 = blockIdx.y * 128;
    int h = blockIdx.x;
    int n0 = h * 64;

    int ar = tid >> 2, ap = (tid & 3) << 3;   // 64 rows x 4 ushort8 each

    const unsigned short* pAh0 = (isq ? Aqh : Vb) + (size_t)(m0 + ar) * K + ap;
    const unsigned short* pAh1 = pAh0 + (size_t)64 * K;
    const unsigned short* pWh  = (isq ? Wqh : Wvh) + (size_t)(n0 + ar) * K + ap;
    const unsigned short* pAl0 = Aql + (size_t)(m0 + ar) * K + ap;
    const unsigned short* pAl1 = pAl0 + (size_t)64 * K;
    const unsigned short* pWl  = Wql + (size_t)(n0 + ar) * K + ap;

    f32x4 acc[2][4];
    #pragma unroll
    for (int mt = 0; mt < 2; ++mt)
        #pragma unroll
        for (int nt = 0; nt < 4; ++nt)
            acc[mt][nt] = (f32x4){0.f, 0.f, 0.f, 0.f};

    ushort8 ra0, ra1, rb0, la0, la1, lb0;
    ra0 = *(const ushort8*)pAh0;
    ra1 = *(const ushort8*)pAh1;
    rb0 = *(const ushort8*)pWh;
    if (isq) {
        la0 = *(const ushort8*)pAl0;
        la1 = *(const ushort8*)pAl1;
        lb0 = *(const ushort8*)pWl;
    }

    for (int kk = 0; kk < K; kk += 32) {
        __syncthreads();
        *(ushort8*)&sAh[ar][ap] = ra0;
        *(ushort8*)&sAh[ar + 64][ap] = ra1;
        *(ushort8*)&sWh[ar][ap] = rb0;
        if (isq) {
            *(ushort8*)&sAl[ar][ap] = la0;
            *(ushort8*)&sAl[ar + 64][ap] = la1;
            *(ushort8*)&sWl[ar][ap] = lb0;
        }
        if (kk + 32 < K) {
            ra0 = *(const ushort8*)(pAh0 + kk + 32);
            ra1 = *(const ushort8*)(pAh1 + kk + 32);
            rb0 = *(const ushort8*)(pWh + kk + 32);
            if (isq) {
                la0 = *(const ushort8*)(pAl0 + kk + 32);
                la1 = *(const ushort8*)(pAl1 + kk + 32);
                lb0 = *(const ushort8*)(pWl + kk + 32);
            }
        }
        __syncthreads();

        bf16x8 af[2], bf[4], afl[2], bfl[4];
        #pragma unroll
        for (int mt = 0; mt < 2; ++mt) {
            af[mt] = *(const bf16x8*)&sAh[w * 32 + mt * 16 + l16][quad * 8];
            if (isq) afl[mt] = *(const bf16x8*)&sAl[w * 32 + mt * 16 + l16][quad * 8];
        }
        #pragma unroll
        for (int nt = 0; nt < 4; ++nt) {
            bf[nt] = *(const bf16x8*)&sWh[nt * 16 + l16][quad * 8];
            if (isq) bfl[nt] = *(const bf16x8*)&sWl[nt * 16 + l16][quad * 8];
        }
        #pragma unroll
        for (int mt = 0; mt < 2; ++mt)
            #pragma unroll
            for (int nt = 0; nt < 4; ++nt) {
                acc[mt][nt] = __builtin_amdgcn_mfma_f32_16x16x32_bf16(af[mt], bf[nt], acc[mt][nt], 0, 0, 0);
                if (isq) {
                    acc[mt][nt] = __builtin_amdgcn_mfma_f32_16x16x32_bf16(afl[mt], bf[nt], acc[mt][nt], 0, 0, 0);
                    acc[mt][nt] = __builtin_amdgcn_mfma_f32_16x16x32_bf16(af[mt], bfl[nt], acc[mt][nt], 0, 0, 0);
                }
            }
    }

    int b = m0 >> 10;

    if (isq) {
        // ---- fused Q'' epilogue: head vals + trig-combined coefs, hi/lo ----
        float bql[4], vbs[2], vbc[2], dti[2];
        #pragma unroll
        for (int nt = 0; nt < 4; ++nt) bql[nt] = bq[h * 64 + nt * 16 + l16];
        #pragma unroll
        for (int t = 0; t < 2; ++t) {
            vbs[t] = v_bias[h * 64 + t * 16 + l16];
            vbc[t] = v_bias[h * 64 + 32 + t * 16 + l16];
            dti[t] = __expf((float)(t * 16 + l16) * DT_CONST);
        }
        #pragma unroll
        for (int mt = 0; mt < 2; ++mt) {
            #pragma unroll
            for (int reg = 0; reg < 4; ++reg) {
                int row = m0 + w * 32 + mt * 16 + quad * 4 + reg;
                int q = row & (SEQ - 1);
                size_t qbase = ((size_t)(b * NH + h) * SEQ + q) * 128;
                float hv[4];
                #pragma unroll
                for (int nt = 0; nt < 4; ++nt) hv[nt] = acc[mt][nt][reg] + bql[nt];
                #pragma unroll
                for (int nt = 0; nt < 4; ++nt) {
                    unsigned short hi, lo;
                    bfsplit(hv[nt], hi, lo);
                    Qh[qbase + nt * 16 + l16] = hi;
                    Ql[qbase + nt * 16 + l16] = lo;
                }
                #pragma unroll
                for (int t = 0; t < 2; ++t) {
                    float u = hv[t] + vbs[t];
                    float wv = hv[t + 2] + vbc[t];
                    float ang = (float)q * dti[t];
                    float C = cosf(ang), S = sinf(ang);
                    float cs = u * C + wv * S;
                    float cc = wv * C - u * S;
                    unsigned short hi, lo;
                    bfsplit(cs, hi, lo);
                    Qh[qbase + 64 + t * 16 + l16] = hi;
                    Ql[qbase + 64 + t * 16 + l16] = lo;
                    bfsplit(cc, hi, lo);
                    Qh[qbase + 96 + t * 16 + l16] = hi;
                    Ql[qbase + 96 + t * 16 + l16] = lo;
                }
            }
        }
    } else {
        // ---- transposed + k-permuted epilogue into vpT[b,h,dd,s] ----
        __syncthreads();
        unsigned short* tb = smem;   // [64][136]
        #pragma unroll
        for (int nt = 0; nt < 4; ++nt) {
            int d = nt * 16 + l16;
            float bcol = bv[n0 + d];
            #pragma unroll
            for (int mt = 0; mt < 2; ++mt)
                #pragma unroll
                for (int reg = 0; reg < 4; ++reg) {
                    int srow = w * 32 + mt * 16 + quad * 4 + reg;
                    tb[d * 136 + srow] = f2bf(acc[mt][nt][reg] + bcol);
                }
        }
        __syncthreads();
        int s0 = m0 & (SEQ - 1);
        #pragma unroll
        for (int i = tid; i < 1024; i += 256) {
            int dd = i >> 4;
            int j16 = i & 15;
            int sb = j16 >> 3;
            int posl = (j16 & 7) << 3;
            unsigned short tmp[8];
            #pragma unroll
            for (int k = 0; k < 8; ++k) {
                int pos = posl + k;
                int sl = (pos >> 2) + (pos & 3) * 16;   // inverse permutation
                tmp[k] = tb[dd * 136 + sb * 64 + sl];
            }
            *(ushort8*)&vpT[((size_t)((b * NH + h) * 64 + dd)) * SEQ + s0 + sb * 64 + posl] =
                *(ushort8*)tmp;
        }
    }
}

// ---------------------------------------------------------------------------
// Output GEMM: out = xab(bf16) @ Woh^T(bf16) + bo, f32 out. Pipelined copies.
// ---------------------------------------------------------------------------
__global__ __launch_bounds__(256) void out_gemm(
    const unsigned short* __restrict__ Ab, const unsigned short* __restrict__ Woh,
    const float* __restrict__ bo, float* __restrict__ C)
{
    __shared__ unsigned short sA[128][32];
    __shared__ unsigned short sW[64][32];

    const int K = DIM, N = DIM;
    int tid = threadIdx.x;
    int lane = tid & 63;
    int w = tid >> 6;
    int l16 = lane & 15, quad = lane >> 4;
    int wm = w & 1, wn = w >> 1;
    int m0 = blockIdx.y * 128, n0 = blockIdx.x * 64;

    int ar = tid >> 2, ap = (tid & 3) << 3;

    const unsigned short* pA0 = Ab + (size_t)(m0 + ar) * K + ap;
    const unsigned short* pA1 = pA0 + (size_t)64 * K;
    const unsigned short* pW  = Woh + (size_t)(n0 + ar) * K + ap;

    f32x4 acc[4][2];
    #pragma unroll
    for (int mt = 0; mt < 4; ++mt)
        #pragma unroll
        for (int nt = 0; nt < 2; ++nt)
            acc[mt][nt] = (f32x4){0.f, 0.f, 0.f, 0.f};

    ushort8 a0 = *(const ushort8*)pA0;
    ushort8 a1 = *(const ushort8*)pA1;
    ushort8 w0 = *(const ushort8*)pW;

    for (int kk = 0; kk < K; kk += 32) {
        __syncthreads();
        *(ushort8*)&sA[ar][ap] = a0;
        *(ushort8*)&sA[ar + 64][ap] = a1;
        *(ushort8*)&sW[ar][ap] = w0;
        if (kk + 32 < K) {
            a0 = *(const ushort8*)(pA0 + kk + 32);
            a1 = *(const ushort8*)(pA1 + kk + 32);
            w0 = *(const ushort8*)(pW + kk + 32);
        }
        __syncthreads();

        bf16x8 af[4], bf[2];
        #pragma unroll
        for (int mt = 0; mt < 4; ++mt)
            af[mt] = *(const bf16x8*)&sA[wm * 64 + mt * 16 + l16][quad * 8];
        #pragma unroll
        for (int nt = 0; nt < 2; ++nt)
            bf[nt] = *(const bf16x8*)&sW[wn * 32 + nt * 16 + l16][quad * 8];
        #pragma unroll
        for (int mt = 0; mt < 4; ++mt)
            #pragma unroll
            for (int nt = 0; nt < 2; ++nt)
                acc[mt][nt] = __builtin_amdgcn_mfma_f32_16x16x32_bf16(af[mt], bf[nt], acc[mt][nt], 0, 0, 0);
    }

    #pragma unroll
    for (int nt = 0; nt < 2; ++nt) {
        int col = n0 + wn * 32 + nt * 16 + l16;
        float bcol = bo[col];
        #pragma unroll
        for (int mt = 0; mt < 4; ++mt)
            #pragma unroll
            for (int reg = 0; reg < 4; ++reg) {
                int row = m0 + wm * 64 + mt * 16 + quad * 4 + reg;
                C[(size_t)row * N + col] = acc[mt][nt][reg] + bcol;
            }
    }
}

// ---------------------------------------------------------------------------
// Flash attention. Block = 256 thr (4 waves), 64 q-rows, one (b,h).
// Register-prefetch pipeline over j-tiles; P stored k-permuted (b64 writes)
// matching the permuted vpT.
// ---------------------------------------------------------------------------
#define LDK 136
#define LDV 72

__global__ __launch_bounds__(256) void attn_mfma(
    const unsigned short* __restrict__ Kh,
    const unsigned short* __restrict__ Kl,
    const unsigned short* __restrict__ vpT,  // [B,H,64,S] (s permuted per 64-blk)
    const unsigned short* __restrict__ Qh,   // [B,H,S,128]
    const unsigned short* __restrict__ Ql,
    const unsigned short* __restrict__ Kth,  // [S,64]
    const unsigned short* __restrict__ Ktl,
    unsigned short* __restrict__ xab)        // [B,S,D] bf16
{
    __shared__ unsigned short Ksh[64][LDK];
    __shared__ unsigned short Ksl[64][LDK];
    __shared__ unsigned short Vt[64][LDV];
    __shared__ unsigned short Ps[64][LDV];

    int tid = threadIdx.x;
    int w = tid >> 6;
    int lane = tid & 63;
    int l16 = lane & 15;
    int quad = lane >> 4;

    int bid = blockIdx.x;
    int qt = bid & 15;
    int h = (bid >> 4) & 15;
    int b = bid >> 8;
    int q0 = qt << 6;

    int sr0 = tid >> 3, sp0 = (tid & 7) << 3;          // stage slot 0 (rows 0..31)
    int sr1 = sr0 + 32;                                 // stage slot 1

    // ---- prefetch j-tile 0 ----
    ushort8 pKh0, pKl0, pTh0, pTl0, pV0, pKh1, pKl1, pTh1, pTl1, pV1;
    {
        size_t g0 = (size_t)(b * SEQ + sr0) * DIM + h * HD + sp0;
        size_t g1 = (size_t)(b * SEQ + sr1) * DIM + h * HD + sp0;
        pKh0 = *(const ushort8*)&Kh[g0]; pKl0 = *(const ushort8*)&Kl[g0];
        pKh1 = *(const ushort8*)&Kh[g1]; pKl1 = *(const ushort8*)&Kl[g1];
        size_t t0 = (size_t)sr0 * 64 + sp0, t1 = (size_t)sr1 * 64 + sp0;
        pTh0 = *(const ushort8*)&Kth[t0]; pTl0 = *(const ushort8*)&Ktl[t0];
        pTh1 = *(const ushort8*)&Kth[t1]; pTl1 = *(const ushort8*)&Ktl[t1];
        size_t v0 = ((size_t)((b * NH + h) * 64 + sr0)) * SEQ + sp0;
        size_t v1 = ((size_t)((b * NH + h) * 64 + sr1)) * SEQ + sp0;
        pV0 = *(const ushort8*)&vpT[v0]; pV1 = *(const ushort8*)&vpT[v1];
    }

    // ---- stage Q'' into Ksh/Ksl, pull A-fragments ----
    {
        const unsigned short* gq = Qh + (((size_t)(b * NH + h)) * SEQ + q0) * 128;
        const unsigned short* gl = Ql + (((size_t)(b * NH + h)) * SEQ + q0) * 128;
        #pragma unroll
        for (int c = tid; c < 1024; c += 256) {
            int r = c >> 4, p = (c & 15) << 3;
            *(ushort8*)&Ksh[r][p] = *(const ushort8*)&gq[r * 128 + p];
            *(ushort8*)&Ksl[r][p] = *(const ushort8*)&gl[r * 128 + p];
        }
    }
    __syncthreads();

    bf16x8 ah[4], al[4];
    #pragma unroll
    for (int c = 0; c < 4; ++c) {
        ah[c] = *(const bf16x8*)&Ksh[w * 16 + l16][c * 32 + quad * 8];
        al[c] = *(const bf16x8*)&Ksl[w * 16 + l16][c * 32 + quad * 8];
    }

    f32x4 oacc[4];
    #pragma unroll
    for (int nb = 0; nb < 4; ++nb) oacc[nb] = (f32x4){0.f, 0.f, 0.f, 0.f};
    float mval[4] = {-INFINITY, -INFINITY, -INFINITY, -INFINITY};
    float lval[4] = {0.f, 0.f, 0.f, 0.f};

    for (int jt = 0; jt < 16; ++jt) {
        __syncthreads();   // prev compute (and Q-frag reads) done with LDS
        *(ushort8*)&Ksh[sr0][sp0] = pKh0;  *(ushort8*)&Ksl[sr0][sp0] = pKl0;
        *(ushort8*)&Ksh[sr1][sp0] = pKh1;  *(ushort8*)&Ksl[sr1][sp0] = pKl1;
        *(ushort8*)&Ksh[sr0][64 + sp0] = pTh0; *(ushort8*)&Ksl[sr0][64 + sp0] = pTl0;
        *(ushort8*)&Ksh[sr1][64 + sp0] = pTh1; *(ushort8*)&Ksl[sr1][64 + sp0] = pTl1;
        *(ushort8*)&Vt[sr0][sp0] = pV0;    *(ushort8*)&Vt[sr1][sp0] = pV1;
        if (jt < 15) {
            int j0n = (jt + 1) << 6;
            size_t g0 = (size_t)(b * SEQ + j0n + sr0) * DIM + h * HD + sp0;
            size_t g1 = (size_t)(b * SEQ + j0n + sr1) * DIM + h * HD + sp0;
            pKh0 = *(const ushort8*)&Kh[g0]; pKl0 = *(const ushort8*)&Kl[g0];
            pKh1 = *(const ushort8*)&Kh[g1]; pKl1 = *(const ushort8*)&Kl[g1];
            size_t t0 = (size_t)(j0n + sr0) * 64 + sp0, t1 = (size_t)(j0n + sr1) * 64 + sp0;
            pTh0 = *(const ushort8*)&Kth[t0]; pTl0 = *(const ushort8*)&Ktl[t0];
            pTh1 = *(const ushort8*)&Kth[t1]; pTl1 = *(const ushort8*)&Ktl[t1];
            size_t v0 = ((size_t)((b * NH + h) * 64 + sr0)) * SEQ + j0n + sp0;
            size_t v1 = ((size_t)((b * NH + h) * 64 + sr1)) * SEQ + j0n + sp0;
            pV0 = *(const ushort8*)&vpT[v0]; pV1 = *(const ushort8*)&vpT[v1];
        }
        __syncthreads();

        // ---- QK^T: S[16 x 64] per wave, split-bf16 ----
        f32x4 sacc[4];
        #pragma unroll
        for (int nb = 0; nb < 4; ++nb) {
            sacc[nb] = (f32x4){0.f, 0.f, 0.f, 0.f};
            #pragma unroll
            for (int c = 0; c < 4; ++c) {
                bf16x8 bh = *(const bf16x8*)&Ksh[nb * 16 + l16][c * 32 + quad * 8];
                bf16x8 bl = *(const bf16x8*)&Ksl[nb * 16 + l16][c * 32 + quad * 8];
                sacc[nb] = __builtin_amdgcn_mfma_f32_16x16x32_bf16(ah[c], bh, sacc[nb], 0, 0, 0);
                sacc[nb] = __builtin_amdgcn_mfma_f32_16x16x32_bf16(al[c], bh, sacc[nb], 0, 0, 0);
                sacc[nb] = __builtin_amdgcn_mfma_f32_16x16x32_bf16(ah[c], bl, sacc[nb], 0, 0, 0);
            }
        }

        // ---- online softmax; P stored k-permuted: pos = l16*4 + c ----
        #pragma unroll
        for (int r = 0; r < 4; ++r) {
            float v = fmaxf(fmaxf(sacc[0][r], sacc[1][r]), fmaxf(sacc[2][r], sacc[3][r]));
            #pragma unroll
            for (int mask = 1; mask < 16; mask <<= 1)
                v = fmaxf(v, __shfl_xor(v, mask, 64));
            float mnew = fmaxf(mval[r], v);
            float alpha = __expf(mval[r] - mnew);
            float p0 = __expf(sacc[0][r] - mnew);
            float p1 = __expf(sacc[1][r] - mnew);
            float p2 = __expf(sacc[2][r] - mnew);
            float p3 = __expf(sacc[3][r] - mnew);
            float rs = (p0 + p1) + (p2 + p3);
            #pragma unroll
            for (int mask = 1; mask < 16; mask <<= 1)
                rs += __shfl_xor(rs, mask, 64);
            lval[r] = lval[r] * alpha + rs;
            mval[r] = mnew;
            int prow = w * 16 + quad * 4 + r;
            ushort4v pv4;
            pv4.x = f2bf(p0); pv4.y = f2bf(p1); pv4.z = f2bf(p2); pv4.w = f2bf(p3);
            *(ushort4v*)&Ps[prow][l16 * 4] = pv4;
            oacc[0][r] *= alpha;
            oacc[1][r] *= alpha;
            oacc[2][r] *= alpha;
            oacc[3][r] *= alpha;
        }
        // each wave reads back only its own 16 Ps rows; Vt stable since barrier

        // ---- PV: O[16 x 64] += P * V (k-space permuted consistently) ----
        #pragma unroll
        for (int nb = 0; nb < 4; ++nb) {
            #pragma unroll
            for (int kc = 0; kc < 2; ++kc) {
                bf16x8 a = *(const bf16x8*)&Ps[w * 16 + l16][kc * 32 + quad * 8];
                bf16x8 bv = *(const bf16x8*)&Vt[nb * 16 + l16][kc * 32 + quad * 8];
                oacc[nb] = __builtin_amdgcn_mfma_f32_16x16x32_bf16(a, bv, oacc[nb], 0, 0, 0);
            }
        }
    }

    // ---- epilogue ----
    #pragma unroll
    for (int r = 0; r < 4; ++r) {
        float inv = 1.f / lval[r];
        int qrow = q0 + w * 16 + quad * 4 + r;
        #pragma unroll
        for (int nb = 0; nb < 4; ++nb) {
            xab[((size_t)(b * SEQ + qrow)) * DIM + h * HD + nb * 16 + l16] = f2bf(oacc[nb][r] * inv);
        }
    }
}

// ---------------------------------------------------------------------------
extern "C" void kernel_launch(void* const* d_in, const int* in_sizes, int n_in,
                              void* d_out, int out_size, void* d_ws, size_t ws_size,
                              hipStream_t stream) {
    const float* query  = (const float*)d_in[0];
    const float* key    = (const float*)d_in[1];
    const float* value  = (const float*)d_in[2];
    // d_in[3]: mask — unused (reference softmax is unmasked)
    const float* Wq     = (const float*)d_in[4];
    const float* bq     = (const float*)d_in[5];
    const float* Wv     = (const float*)d_in[6];
    const float* bv     = (const float*)d_in[7];
    const float* Wo     = (const float*)d_in[8];
    const float* bo     = (const float*)d_in[9];
    const float* v_bias = (const float*)d_in[10];

    float* out = (float*)d_out;
    char* base = (char*)d_ws;
    const size_t MB = 1024 * 1024;

    // xab aliases Aqh: Aqh consumed by qv_gemm; xab written by attn (later).
    unsigned short* Aqh = (unsigned short*)base;             // 4 MB
    unsigned short* xab = (unsigned short*)base;             // 4 MB (alias)
    unsigned short* Aql = (unsigned short*)(base + 4 * MB);  // 4 MB
    unsigned short* vpT = (unsigned short*)(base + 8 * MB);  // 4 MB
    unsigned short* Khs = (unsigned short*)(base + 12 * MB); // 4 MB
    unsigned short* Kls = (unsigned short*)(base + 16 * MB); // 4 MB
    unsigned short* Qh  = (unsigned short*)(base + 20 * MB); // 8 MB
    unsigned short* Ql  = (unsigned short*)(base + 28 * MB); // 8 MB
    unsigned short* Wqh = (unsigned short*)(base + 36 * MB); // 2 MB
    unsigned short* Wql = (unsigned short*)(base + 38 * MB); // 2 MB
    unsigned short* Vb  = (unsigned short*)(base + 40 * MB); // 4 MB
    unsigned short* Wvh = (unsigned short*)(base + 44 * MB); // 2 MB
    unsigned short* Woh = (unsigned short*)(base + 46 * MB); // 2 MB
    unsigned short* Kth = (unsigned short*)(base + 48 * MB); // 128 KB
    unsigned short* Ktl = Kth + (size_t)SEQ * 64;            // 128 KB

    const int M = NB * SEQ;

    prep_ktrig<<<SEQ * 64 / 256, 256, 0, stream>>>(Kth, Ktl);

    dim3 cgrid(M * DIM / 2048, 6);
    conv_all<<<cgrid, 256, 0, stream>>>(query, key, value, Wq, Wv, Wo,
                                        Aqh, Aql, Khs, Kls, Vb, Wqh, Wql, Wvh, Woh);

    dim3 qvgrid(DIM / 64, M / 128, 2);
    qv_gemm<<<qvgrid, 256, 0, stream>>>(Aqh, Aql, Wqh, Wql, bq, Vb, Wvh, bv,
                                        v_bias, Qh, Ql, vpT);

    attn_mfma<<<NB * NH * (SEQ / 64), 256, 0, stream>>>(Khs, Kls, vpT, Qh, Ql, Kth, Ktl, xab);

    dim3 ogrid(DIM / 64, M / 128);
    out_gemm<<<ogrid, 256, 0, stream>>>(xab, Woh, bo, out);
}